// Round 1
// baseline (4367.396 us; speedup 1.0000x reference)
//
#include <hip/hip_runtime.h>
#include <hip/hip_bf16.h>

#define NNODES 100000
#define NEDGES 1600000

// ---------------------------------------------------------------------------
// GEMM: C_l = A @ Bl, C_r = A @ Br   (A: nrows x 128, B*: 128 x COLS)
// Block = 256 threads, 64 rows of A per block staged in LDS.
// Thread (cx = tid % COLS, part = tid / COLS) computes COLS/ (256/COLS) ... :
//   RP = COLS/4 rows for both outputs -> accL[RP], accR[RP].
// LDS reads are wave-uniform (broadcast, conflict-free); B reads coalesced.
// ---------------------------------------------------------------------------
template <int COLS>
__global__ __launch_bounds__(256) void gemm_dual(
    const float* __restrict__ A, const float* __restrict__ Bl,
    const float* __restrict__ Br, float* __restrict__ Cl,
    float* __restrict__ Cr, int nrows) {
  constexpr int PARTS = 256 / COLS;   // 2 for COLS=128, 4 for COLS=64
  constexpr int RP = 64 / PARTS;      // rows per part: 32 / 16
  __shared__ float At[64][132];       // 132*4 = 528B row stride (16B aligned)

  const int tid = threadIdx.x;
  const int row0 = blockIdx.x * 64;

  // stage A tile (float4 loads, zero-fill past nrows)
  for (int i = tid; i < 64 * 32; i += 256) {
    int r = i >> 5;
    int k4 = (i & 31) << 2;
    float4 v = make_float4(0.f, 0.f, 0.f, 0.f);
    int gr = row0 + r;
    if (gr < nrows) v = *(const float4*)(A + (size_t)gr * 128 + k4);
    *(float4*)&At[r][k4] = v;
  }
  __syncthreads();

  const int cx = tid % COLS;
  const int part = tid / COLS;
  const int rbase = part * RP;

  float accL[RP];
  float accR[RP];
#pragma unroll
  for (int r = 0; r < RP; ++r) { accL[r] = 0.f; accR[r] = 0.f; }

  for (int k = 0; k < 128; k += 4) {
    float bl0 = Bl[(k + 0) * COLS + cx];
    float bl1 = Bl[(k + 1) * COLS + cx];
    float bl2 = Bl[(k + 2) * COLS + cx];
    float bl3 = Bl[(k + 3) * COLS + cx];
    float br0 = Br[(k + 0) * COLS + cx];
    float br1 = Br[(k + 1) * COLS + cx];
    float br2 = Br[(k + 2) * COLS + cx];
    float br3 = Br[(k + 3) * COLS + cx];
#pragma unroll
    for (int r = 0; r < RP; ++r) {
      float4 a = *(const float4*)&At[rbase + r][k];
      accL[r] = fmaf(a.w, bl3, fmaf(a.z, bl2, fmaf(a.y, bl1, fmaf(a.x, bl0, accL[r]))));
      accR[r] = fmaf(a.w, br3, fmaf(a.z, br2, fmaf(a.y, br1, fmaf(a.x, br0, accR[r]))));
    }
  }

#pragma unroll
  for (int r = 0; r < RP; ++r) {
    int gr = row0 + rbase + r;
    if (gr < nrows) {
      Cl[(size_t)gr * COLS + cx] = accL[r];
      Cr[(size_t)gr * COLS + cx] = accR[r];
    }
  }
}

// ---------------------------------------------------------------------------
// Edge aggregation: agg[dst] += feat[src] (scatter-add via HW f32 atomics).
// One float4 (4 cols) per work item; CSHIFT: log2(cols) (7 -> 128, 6 -> 64).
// Optionally accumulates degree (layer 1 only).
// ---------------------------------------------------------------------------
template <int CSHIFT>
__global__ __launch_bounds__(256) void edge_agg(
    const int* __restrict__ ei, const float* __restrict__ feat,
    float* __restrict__ agg, float* __restrict__ deg, int nE) {
  constexpr int Q = 1 << (CSHIFT - 2);  // float4s per row
  const long long work = (long long)nE * Q;
  const long long stride = (long long)gridDim.x * blockDim.x;
  for (long long idx = (long long)blockIdx.x * blockDim.x + threadIdx.x;
       idx < work; idx += stride) {
    int e = (int)(idx >> (CSHIFT - 2));
    int q = (int)(idx & (Q - 1));
    int src = ei[e];
    int dst = ei[nE + e];
    const float4 v = *(const float4*)(feat + ((size_t)src << CSHIFT) + (q << 2));
    float* p = agg + ((size_t)dst << CSHIFT) + (q << 2);
    unsafeAtomicAdd(p + 0, v.x);
    unsafeAtomicAdd(p + 1, v.y);
    unsafeAtomicAdd(p + 2, v.z);
    unsafeAtomicAdd(p + 3, v.w);
    if (deg != nullptr && q == 0) unsafeAtomicAdd(deg + dst, 1.0f);
  }
}

// ---------------------------------------------------------------------------
// h = relu(LN(agg/deg + b1l + r1))  — one 64-lane wave per row (128 cols).
// ---------------------------------------------------------------------------
__global__ __launch_bounds__(256) void ln_relu_kernel(
    const float* __restrict__ agg, const float* __restrict__ r1,
    const float* __restrict__ deg, const float* __restrict__ b1l,
    const float* __restrict__ g, const float* __restrict__ b,
    float* __restrict__ h) {
  int row = blockIdx.x * 4 + (threadIdx.x >> 6);
  int lane = threadIdx.x & 63;
  if (row >= NNODES) return;
  float inv = 1.0f / fmaxf(deg[row], 1.0f);
  size_t base = (size_t)row * 128;
  float a0 = agg[base + lane] * inv + b1l[lane] + r1[base + lane];
  float a1 = agg[base + lane + 64] * inv + b1l[lane + 64] + r1[base + lane + 64];
  float s = a0 + a1;
#pragma unroll
  for (int m = 32; m >= 1; m >>= 1) s += __shfl_xor(s, m);
  float mu = s * (1.0f / 128.0f);
  float d0 = a0 - mu, d1 = a1 - mu;
  float v = d0 * d0 + d1 * d1;
#pragma unroll
  for (int m = 32; m >= 1; m >>= 1) v += __shfl_xor(v, m);
  float rstd = rsqrtf(v * (1.0f / 128.0f) + 1e-5f);
  h[base + lane] = fmaxf(d0 * rstd * g[lane] + b[lane], 0.0f);
  h[base + lane + 64] = fmaxf(d1 * rstd * g[lane + 64] + b[lane + 64], 0.0f);
}

// ---------------------------------------------------------------------------
// out = l2normalize(agg/deg + b2l + r2) — one wave per row (64 cols).
// ---------------------------------------------------------------------------
__global__ __launch_bounds__(256) void out_norm_kernel(
    const float* __restrict__ agg, const float* __restrict__ r2,
    const float* __restrict__ deg, const float* __restrict__ b2l,
    float* __restrict__ out) {
  int row = blockIdx.x * 4 + (threadIdx.x >> 6);
  int lane = threadIdx.x & 63;
  if (row >= NNODES) return;
  float inv = 1.0f / fmaxf(deg[row], 1.0f);
  size_t base = (size_t)row * 64;
  float v = agg[base + lane] * inv + b2l[lane] + r2[base + lane];
  float s = v * v;
#pragma unroll
  for (int m = 32; m >= 1; m >>= 1) s += __shfl_xor(s, m);
  float nrm = sqrtf(s);
  out[base + lane] = v / fmaxf(nrm, 1e-12f);
}

extern "C" void kernel_launch(void* const* d_in, const int* in_sizes, int n_in,
                              void* d_out, int out_size, void* d_ws, size_t ws_size,
                              hipStream_t stream) {
  const float* x   = (const float*)d_in[0];
  const int*   ei  = (const int*)d_in[1];
  const float* W1l = (const float*)d_in[2];
  const float* b1l = (const float*)d_in[3];
  const float* W1r = (const float*)d_in[4];
  const float* lng = (const float*)d_in[5];
  const float* lnb = (const float*)d_in[6];
  const float* W2l = (const float*)d_in[7];
  const float* b2l = (const float*)d_in[8];
  const float* W2r = (const float*)d_in[9];
  float* out = (float*)d_out;

  const int N = NNODES, E = NEDGES;
  // Workspace layout (floats); total = 3*N*128 + N = 38.5M floats = 154 MB.
  float* ws  = (float*)d_ws;
  float* y1  = ws;                       // N*128: x@W1l, later reused as h
  float* r1  = ws + (size_t)N * 128;     // N*128: x@W1r, later z2 (N*64) + r2 (N*64)
  float* agg = ws + (size_t)2 * N * 128; // N*128: agg1, then agg2 (N*64)
  float* deg = ws + (size_t)3 * N * 128; // N

  hipMemsetAsync(agg, 0, (size_t)N * 128 * sizeof(float), stream);
  hipMemsetAsync(deg, 0, (size_t)N * sizeof(float), stream);

  const int gemm_blocks = (N + 63) / 64;  // 1563

  // Layer 1: y1 = x@W1l, r1 = x@W1r; aggregate y1 (matmul is linear, so
  // mean-agg after the GEMM); then h = relu(LN(agg/deg + b1l + r1)).
  gemm_dual<128><<<gemm_blocks, 256, 0, stream>>>(x, W1l, W1r, y1, r1, N);
  edge_agg<7><<<12288, 256, 0, stream>>>(ei, y1, agg, deg, E);
  ln_relu_kernel<<<(N + 3) / 4, 256, 0, stream>>>(agg, r1, deg, b1l, lng, lnb, y1);

  // Layer 2: z2 = h@W2l (64 cols — half the edge traffic of aggregating h),
  // r2 = h@W2r; aggregate z2; out = l2norm(agg/deg + b2l + r2).
  float* z2 = r1;
  float* r2 = r1 + (size_t)N * 64;
  gemm_dual<64><<<gemm_blocks, 256, 0, stream>>>(y1, W2l, W2r, z2, r2, N);
  hipMemsetAsync(agg, 0, (size_t)N * 64 * sizeof(float), stream);
  edge_agg<6><<<12288, 256, 0, stream>>>(ei, z2, agg, nullptr, E);
  out_norm_kernel<<<(N + 3) / 4, 256, 0, stream>>>(agg, r2, deg, b2l, out);
}

// Round 2
// 590.101 us; speedup vs baseline: 7.4011x; 7.4011x over previous
//
#include <hip/hip_runtime.h>
#include <hip/hip_bf16.h>

#define NNODES 100000
#define NEDGES 1600000
#define NB_SCAN 391  // ceil(NNODES/256)

// ---------------------------------------------------------------------------
// GEMM: C_l = A @ Bl, C_r = A @ Br   (A: nrows x 128, B*: 128 x COLS)
// Block = 256 threads, 64 rows of A per block staged in LDS.
// ---------------------------------------------------------------------------
template <int COLS>
__global__ __launch_bounds__(256) void gemm_dual(
    const float* __restrict__ A, const float* __restrict__ Bl,
    const float* __restrict__ Br, float* __restrict__ Cl,
    float* __restrict__ Cr, int nrows) {
  constexpr int PARTS = 256 / COLS;   // 2 for COLS=128, 4 for COLS=64
  constexpr int RP = 64 / PARTS;      // rows per part: 32 / 16
  __shared__ float At[64][132];

  const int tid = threadIdx.x;
  const int row0 = blockIdx.x * 64;

  for (int i = tid; i < 64 * 32; i += 256) {
    int r = i >> 5;
    int k4 = (i & 31) << 2;
    float4 v = make_float4(0.f, 0.f, 0.f, 0.f);
    int gr = row0 + r;
    if (gr < nrows) v = *(const float4*)(A + (size_t)gr * 128 + k4);
    *(float4*)&At[r][k4] = v;
  }
  __syncthreads();

  const int cx = tid % COLS;
  const int part = tid / COLS;
  const int rbase = part * RP;

  float accL[RP], accR[RP];
#pragma unroll
  for (int r = 0; r < RP; ++r) { accL[r] = 0.f; accR[r] = 0.f; }

  for (int k = 0; k < 128; k += 4) {
    float bl0 = Bl[(k + 0) * COLS + cx];
    float bl1 = Bl[(k + 1) * COLS + cx];
    float bl2 = Bl[(k + 2) * COLS + cx];
    float bl3 = Bl[(k + 3) * COLS + cx];
    float br0 = Br[(k + 0) * COLS + cx];
    float br1 = Br[(k + 1) * COLS + cx];
    float br2 = Br[(k + 2) * COLS + cx];
    float br3 = Br[(k + 3) * COLS + cx];
#pragma unroll
    for (int r = 0; r < RP; ++r) {
      float4 a = *(const float4*)&At[rbase + r][k];
      accL[r] = fmaf(a.w, bl3, fmaf(a.z, bl2, fmaf(a.y, bl1, fmaf(a.x, bl0, accL[r]))));
      accR[r] = fmaf(a.w, br3, fmaf(a.z, br2, fmaf(a.y, br1, fmaf(a.x, br0, accR[r]))));
    }
  }

#pragma unroll
  for (int r = 0; r < RP; ++r) {
    int gr = row0 + rbase + r;
    if (gr < nrows) {
      Cl[(size_t)gr * COLS + cx] = accL[r];
      Cr[(size_t)gr * COLS + cx] = accR[r];
    }
  }
}

// ---------------------------------------------------------------------------
// CSR build: count -> 2-level exclusive scan -> fill (int atomics only).
// ---------------------------------------------------------------------------
__global__ __launch_bounds__(256) void count_kernel(const int* __restrict__ ei,
                                                    int* __restrict__ cnt) {
  int stride = gridDim.x * blockDim.x;
  for (int e = blockIdx.x * blockDim.x + threadIdx.x; e < NEDGES; e += stride)
    atomicAdd(&cnt[ei[NEDGES + e]], 1);
}

__global__ __launch_bounds__(256) void scan_a(const int* __restrict__ cnt,
                                              int* __restrict__ excl,
                                              int* __restrict__ bsums) {
  __shared__ int sm[256];
  int t = threadIdx.x;
  int i = blockIdx.x * 256 + t;
  int v = (i < NNODES) ? cnt[i] : 0;
  int acc = v;
  sm[t] = acc;
  __syncthreads();
  for (int off = 1; off < 256; off <<= 1) {
    int add = (t >= off) ? sm[t - off] : 0;
    __syncthreads();
    acc += add;
    sm[t] = acc;
    __syncthreads();
  }
  if (i < NNODES) excl[i] = acc - v;
  if (t == 255) bsums[blockIdx.x] = acc;
}

__global__ __launch_bounds__(512) void scan_b(int* __restrict__ bsums) {
  __shared__ int sm[512];
  int t = threadIdx.x;
  int v = (t < NB_SCAN) ? bsums[t] : 0;
  int acc = v;
  sm[t] = acc;
  __syncthreads();
  for (int off = 1; off < 512; off <<= 1) {
    int add = (t >= off) ? sm[t - off] : 0;
    __syncthreads();
    acc += add;
    sm[t] = acc;
    __syncthreads();
  }
  if (t < NB_SCAN) bsums[t] = acc - v;  // exclusive
}

__global__ __launch_bounds__(256) void scan_c(int* __restrict__ rowptr,
                                              int* __restrict__ cursor,
                                              const int* __restrict__ bsums) {
  int i = blockIdx.x * 256 + threadIdx.x;
  if (i < NNODES) {
    int val = rowptr[i] + bsums[blockIdx.x];
    rowptr[i] = val;
    cursor[i] = val;
  }
  if (i == 0) rowptr[NNODES] = NEDGES;
}

__global__ __launch_bounds__(256) void fill_kernel(const int* __restrict__ ei,
                                                   int* __restrict__ cursor,
                                                   int* __restrict__ adj) {
  int stride = gridDim.x * blockDim.x;
  for (int e = blockIdx.x * blockDim.x + threadIdx.x; e < NEDGES; e += stride) {
    int dst = ei[NEDGES + e];
    int pos = atomicAdd(&cursor[dst], 1);
    adj[pos] = ei[e];
  }
}

// ---------------------------------------------------------------------------
// Layer-1 gather + epilogue: h = relu(LN(mean_agg(y1) + b1l + r1)).
// One 64-lane wave per node; lane holds cols {2*lane, 2*lane+1}.
// Writes h IN PLACE over r1 (each wave touches only its own row).
// ---------------------------------------------------------------------------
__global__ __launch_bounds__(256) void gather_ln_relu(
    const int* __restrict__ rowptr, const int* __restrict__ adj,
    const float* __restrict__ feat, float* __restrict__ hres,
    const float* __restrict__ b1l, const float* __restrict__ g,
    const float* __restrict__ b) {
  int row = blockIdx.x * 4 + (threadIdx.x >> 6);
  if (row >= NNODES) return;
  int lane = threadIdx.x & 63;
  int e0 = rowptr[row], e1 = rowptr[row + 1];
  float ax = 0.f, ay = 0.f;
  int e = e0;
  for (; e + 4 <= e1; e += 4) {  // 4 independent loads in flight
    int s0 = adj[e], s1 = adj[e + 1], s2 = adj[e + 2], s3 = adj[e + 3];
    float2 v0 = *(const float2*)(feat + ((size_t)s0 << 7) + lane * 2);
    float2 v1 = *(const float2*)(feat + ((size_t)s1 << 7) + lane * 2);
    float2 v2 = *(const float2*)(feat + ((size_t)s2 << 7) + lane * 2);
    float2 v3 = *(const float2*)(feat + ((size_t)s3 << 7) + lane * 2);
    ax += (v0.x + v1.x) + (v2.x + v3.x);
    ay += (v0.y + v1.y) + (v2.y + v3.y);
  }
  for (; e < e1; ++e) {
    int s0 = adj[e];
    float2 v0 = *(const float2*)(feat + ((size_t)s0 << 7) + lane * 2);
    ax += v0.x;
    ay += v0.y;
  }
  float inv = 1.0f / fmaxf((float)(e1 - e0), 1.0f);
  int c0 = lane * 2, c1 = c0 + 1;
  size_t base = (size_t)row * 128;
  float a0 = ax * inv + b1l[c0] + hres[base + c0];
  float a1 = ay * inv + b1l[c1] + hres[base + c1];
  float s = a0 + a1;
#pragma unroll
  for (int m = 32; m >= 1; m >>= 1) s += __shfl_xor(s, m);
  float mu = s * (1.0f / 128.0f);
  float d0 = a0 - mu, d1 = a1 - mu;
  float v = d0 * d0 + d1 * d1;
#pragma unroll
  for (int m = 32; m >= 1; m >>= 1) v += __shfl_xor(v, m);
  float rstd = rsqrtf(v * (1.0f / 128.0f) + 1e-5f);
  hres[base + c0] = fmaxf(d0 * rstd * g[c0] + b[c0], 0.0f);
  hres[base + c1] = fmaxf(d1 * rstd * g[c1] + b[c1], 0.0f);
}

// ---------------------------------------------------------------------------
// Layer-2 gather + epilogue: out = l2norm(mean_agg(z2) + b2l + r2).
// One wave per node; lane holds col lane (64 cols).
// ---------------------------------------------------------------------------
__global__ __launch_bounds__(256) void gather_l2norm(
    const int* __restrict__ rowptr, const int* __restrict__ adj,
    const float* __restrict__ z2, const float* __restrict__ r2,
    const float* __restrict__ b2l, float* __restrict__ out) {
  int row = blockIdx.x * 4 + (threadIdx.x >> 6);
  if (row >= NNODES) return;
  int lane = threadIdx.x & 63;
  int e0 = rowptr[row], e1 = rowptr[row + 1];
  float acc = 0.f;
  int e = e0;
  for (; e + 4 <= e1; e += 4) {
    int s0 = adj[e], s1 = adj[e + 1], s2 = adj[e + 2], s3 = adj[e + 3];
    float v0 = z2[((size_t)s0 << 6) + lane];
    float v1 = z2[((size_t)s1 << 6) + lane];
    float v2 = z2[((size_t)s2 << 6) + lane];
    float v3 = z2[((size_t)s3 << 6) + lane];
    acc += (v0 + v1) + (v2 + v3);
  }
  for (; e < e1; ++e) acc += z2[((size_t)adj[e] << 6) + lane];
  float inv = 1.0f / fmaxf((float)(e1 - e0), 1.0f);
  size_t base = (size_t)row * 64;
  float val = acc * inv + b2l[lane] + r2[base + lane];
  float s = val * val;
#pragma unroll
  for (int m = 32; m >= 1; m >>= 1) s += __shfl_xor(s, m);
  float nrm = fmaxf(sqrtf(s), 1e-12f);
  out[base + lane] = val / nrm;
}

extern "C" void kernel_launch(void* const* d_in, const int* in_sizes, int n_in,
                              void* d_out, int out_size, void* d_ws, size_t ws_size,
                              hipStream_t stream) {
  const float* x   = (const float*)d_in[0];
  const int*   ei  = (const int*)d_in[1];
  const float* W1l = (const float*)d_in[2];
  const float* b1l = (const float*)d_in[3];
  const float* W1r = (const float*)d_in[4];
  const float* lng = (const float*)d_in[5];
  const float* lnb = (const float*)d_in[6];
  const float* W2l = (const float*)d_in[7];
  const float* b2l = (const float*)d_in[8];
  const float* W2r = (const float*)d_in[9];
  float* out = (float*)d_out;

  const int N = NNODES, E = NEDGES;

  // Workspace layout: f0 (N*128 fl), f1 (N*128 fl), then ints
  // rowptr (N+1), cursor (N), adj (E), bsums (NB_SCAN). Total ~110 MB.
  float* f0 = (float*)d_ws;                 // y1; later z2 (N*64) + r2 (N*64)
  float* f1 = f0 + (size_t)N * 128;         // r1; overwritten in place by h
  int* rowptr = (int*)(f1 + (size_t)N * 128);
  int* cursor = rowptr + (N + 1);
  int* adj    = cursor + N;
  int* bsums  = adj + E;

  hipMemsetAsync(cursor, 0, (size_t)N * sizeof(int), stream);

  // CSR build (int atomics only)
  count_kernel<<<4096, 256, 0, stream>>>(ei, cursor);
  scan_a<<<NB_SCAN, 256, 0, stream>>>(cursor, rowptr, bsums);
  scan_b<<<1, 512, 0, stream>>>(bsums);
  scan_c<<<NB_SCAN, 256, 0, stream>>>(rowptr, cursor, bsums);
  fill_kernel<<<4096, 256, 0, stream>>>(ei, cursor, adj);

  const int gemm_blocks = (N + 63) / 64;
  const int node_blocks = (N + 3) / 4;

  // Layer 1: y1 = x@W1l, r1 = x@W1r; pull-aggregate y1 per dst (linearity
  // lets us aggregate after the GEMM); fused mean+bias+residual+LN+ReLU.
  gemm_dual<128><<<gemm_blocks, 256, 0, stream>>>(x, W1l, W1r, f0, f1, N);
  gather_ln_relu<<<node_blocks, 256, 0, stream>>>(rowptr, adj, f0, f1, b1l, lng, lnb);

  // Layer 2: z2 = h@W2l (64 cols halves gather traffic), r2 = h@W2r;
  // pull-aggregate z2; fused mean+bias+residual+L2norm -> out.
  float* z2 = f0;
  float* r2 = f0 + (size_t)N * 64;
  gemm_dual<64><<<gemm_blocks, 256, 0, stream>>>(f1, W2l, W2r, z2, r2, N);
  gather_l2norm<<<node_blocks, 256, 0, stream>>>(rowptr, adj, z2, r2, b2l, out);
}

// Round 3
// 408.221 us; speedup vs baseline: 10.6986x; 1.4455x over previous
//
#include <hip/hip_runtime.h>
#include <hip/hip_bf16.h>

#define NNODES 100000
#define NEDGES 1600000
#define NB_SCAN 391  // ceil(NNODES/256)

typedef short short8 __attribute__((ext_vector_type(8)));
typedef float floatx4 __attribute__((ext_vector_type(4)));

__device__ inline float bf2f_lo(unsigned int v) {
  union { unsigned int i; float f; } u; u.i = v << 16; return u.f;
}
__device__ inline float bf2f_hi(unsigned int v) {
  union { unsigned int i; float f; } u; u.i = v & 0xffff0000u; return u.f;
}
__device__ inline float bf2f(unsigned short s) {
  union { unsigned int i; float f; } u; u.i = ((unsigned int)s) << 16; return u.f;
}
__device__ inline unsigned short f2bf(float f) {  // RNE
  union { float f; unsigned int i; } u; u.f = f;
  unsigned int r = u.i + 0x7fffu + ((u.i >> 16) & 1u);
  return (unsigned short)(r >> 16);
}

// ---------------------------------------------------------------------------
// Weight prep: Bcat = [Wl | Wr] (128 x 2*half) cast to bf16 and laid out
// fragment-contiguous: Bswz[((ct*4+ks)*64 + lane)*8 + j] = Bcat[k][c],
// k = ks*32 + (lane>>4)*8 + j, c = ct*16 + (lane&15).
// GEMM waves then load B panels with coalesced 16B loads.
// ---------------------------------------------------------------------------
__global__ __launch_bounds__(256) void prep_b(const float* __restrict__ Wl,
                                              const float* __restrict__ Wr,
                                              short* __restrict__ Bswz, int half) {
  int total = 128 * 2 * half;
  int stride = gridDim.x * 256;
  for (int i = blockIdx.x * 256 + threadIdx.x; i < total; i += stride) {
    int j = i & 7;
    int lane = (i >> 3) & 63;
    int f = i >> 9;  // frag id = ct*4 + ks
    int ks = f & 3, ct = f >> 2;
    int k = ks * 32 + ((lane >> 4) << 3) + j;
    int c = ct * 16 + (lane & 15);
    float v = (c < half) ? Wl[k * half + c] : Wr[k * half + (c - half)];
    Bswz[i] = (short)f2bf(v);
  }
}

// ---------------------------------------------------------------------------
// MFMA GEMM: C = A @ Bcat, A: nrows x 128 (fp32 or bf16), Bcat: 128 x NCOLS.
// Block = 256 thr (4 waves), 64 rows/block. Wave w owns cols [w*PW, w*PW+PW).
// Swapped operands (B as A-operand) -> lane holds 4 consecutive cols of one
// row -> packed bf16 ushort4 stores. Cols < NCOLS/2 -> outL, else -> outR.
// ---------------------------------------------------------------------------
template <int NCOLS, bool ABF16>
__global__ __launch_bounds__(256) void gemm_mfma(
    const void* __restrict__ Av, const short* __restrict__ Bswz,
    unsigned short* __restrict__ outL, unsigned short* __restrict__ outR,
    int nrows) {
  constexpr int PW = NCOLS / 4;   // cols per wave
  constexpr int CT = PW / 16;     // 16-col tiles per wave
  constexpr int HALF = NCOLS / 2;
  __shared__ unsigned short At[64][136];  // bf16, +16B pad per row

  const int tid = threadIdx.x;
  const int lane = tid & 63;
  const int wave = tid >> 6;
  const int row0 = blockIdx.x * 64;

  if (ABF16) {
    const unsigned short* A = (const unsigned short*)Av;
    for (int i = tid; i < 64 * 16; i += 256) {
      int r = i >> 4, c8 = (i & 15) << 3;
      int gr = row0 + r;
      uint4 v = make_uint4(0, 0, 0, 0);
      if (gr < nrows) v = *(const uint4*)(A + (size_t)gr * 128 + c8);
      *(uint4*)&At[r][c8] = v;
    }
  } else {
    const float* A = (const float*)Av;
    for (int i = tid; i < 64 * 32; i += 256) {
      int r = i >> 5, c4 = (i & 31) << 2;
      int gr = row0 + r;
      float4 v = make_float4(0.f, 0.f, 0.f, 0.f);
      if (gr < nrows) v = *(const float4*)(A + (size_t)gr * 128 + c4);
      ushort4 u = make_ushort4(f2bf(v.x), f2bf(v.y), f2bf(v.z), f2bf(v.w));
      *(ushort4*)&At[r][c4] = u;
    }
  }
  __syncthreads();

  short8 bfrag[CT][4];
#pragma unroll
  for (int ct = 0; ct < CT; ++ct)
#pragma unroll
    for (int ks = 0; ks < 4; ++ks)
      bfrag[ct][ks] =
          *(const short8*)(Bswz + ((((wave * CT + ct) * 4 + ks) * 64 + lane) << 3));

  floatx4 acc[4][CT];
#pragma unroll
  for (int rt = 0; rt < 4; ++rt)
#pragma unroll
    for (int ct = 0; ct < CT; ++ct) acc[rt][ct] = (floatx4)(0.f);

#pragma unroll
  for (int rt = 0; rt < 4; ++rt) {
#pragma unroll
    for (int ks = 0; ks < 4; ++ks) {
      short8 af = *(const short8*)&At[rt * 16 + (lane & 15)][ks * 32 + ((lane >> 4) << 3)];
#pragma unroll
      for (int ct = 0; ct < CT; ++ct)
        acc[rt][ct] = __builtin_amdgcn_mfma_f32_16x16x32_bf16(
            bfrag[ct][ks], af, acc[rt][ct], 0, 0, 0);
    }
  }

#pragma unroll
  for (int rt = 0; rt < 4; ++rt) {
    int gr = row0 + rt * 16 + (lane & 15);
    if (gr >= nrows) continue;
#pragma unroll
    for (int ct = 0; ct < CT; ++ct) {
      int col = wave * PW + ct * 16 + ((lane >> 4) << 2);
      unsigned short* buf = (col < HALF) ? outL : outR;  // wave-uniform
      int c = col & (HALF - 1);
      floatx4 a = acc[rt][ct];
      ushort4 u = make_ushort4(f2bf(a[0]), f2bf(a[1]), f2bf(a[2]), f2bf(a[3]));
      *(ushort4*)(buf + (size_t)gr * HALF + c) = u;
    }
  }
}

// ---------------------------------------------------------------------------
// CSR build: count -> 2-level exclusive scan -> fill (int atomics only).
// ---------------------------------------------------------------------------
__global__ __launch_bounds__(256) void count_kernel(const int* __restrict__ ei,
                                                    int* __restrict__ cnt) {
  int stride = gridDim.x * blockDim.x;
  for (int e = blockIdx.x * blockDim.x + threadIdx.x; e < NEDGES; e += stride)
    atomicAdd(&cnt[ei[NEDGES + e]], 1);
}

__global__ __launch_bounds__(256) void scan_a(const int* __restrict__ cnt,
                                              int* __restrict__ excl,
                                              int* __restrict__ bsums) {
  __shared__ int sm[256];
  int t = threadIdx.x;
  int i = blockIdx.x * 256 + t;
  int v = (i < NNODES) ? cnt[i] : 0;
  int acc = v;
  sm[t] = acc;
  __syncthreads();
  for (int off = 1; off < 256; off <<= 1) {
    int add = (t >= off) ? sm[t - off] : 0;
    __syncthreads();
    acc += add;
    sm[t] = acc;
    __syncthreads();
  }
  if (i < NNODES) excl[i] = acc - v;
  if (t == 255) bsums[blockIdx.x] = acc;
}

__global__ __launch_bounds__(512) void scan_b(int* __restrict__ bsums) {
  __shared__ int sm[512];
  int t = threadIdx.x;
  int v = (t < NB_SCAN) ? bsums[t] : 0;
  int acc = v;
  sm[t] = acc;
  __syncthreads();
  for (int off = 1; off < 512; off <<= 1) {
    int add = (t >= off) ? sm[t - off] : 0;
    __syncthreads();
    acc += add;
    sm[t] = acc;
    __syncthreads();
  }
  if (t < NB_SCAN) bsums[t] = acc - v;  // exclusive
}

__global__ __launch_bounds__(256) void scan_c(int* __restrict__ rowptr,
                                              int* __restrict__ cursor,
                                              const int* __restrict__ bsums) {
  int i = blockIdx.x * 256 + threadIdx.x;
  if (i < NNODES) {
    int val = rowptr[i] + bsums[blockIdx.x];
    rowptr[i] = val;
    cursor[i] = val;
  }
  if (i == 0) rowptr[NNODES] = NEDGES;
}

__global__ __launch_bounds__(256) void fill_kernel(const int* __restrict__ ei,
                                                   int* __restrict__ cursor,
                                                   int* __restrict__ adj) {
  int stride = gridDim.x * blockDim.x;
  for (int e = blockIdx.x * blockDim.x + threadIdx.x; e < NEDGES; e += stride) {
    int dst = ei[NEDGES + e];
    int pos = atomicAdd(&cursor[dst], 1);
    adj[pos] = ei[e];
  }
}

// ---------------------------------------------------------------------------
// Layer-1 gather + epilogue: h = relu(LN(mean_agg(y1) + b1l + r1)).
// One wave per node; lane holds cols {2l, 2l+1} (one dword of bf16x2).
// h overwrites r1 in place (bf16).
// ---------------------------------------------------------------------------
__global__ __launch_bounds__(256) void gather_ln_relu(
    const int* __restrict__ rowptr, const int* __restrict__ adj,
    const unsigned short* __restrict__ feat, unsigned short* __restrict__ hres,
    const float* __restrict__ b1l, const float* __restrict__ g,
    const float* __restrict__ b) {
  int row = blockIdx.x * 4 + (threadIdx.x >> 6);
  if (row >= NNODES) return;
  int lane = threadIdx.x & 63;
  int e0 = rowptr[row], e1 = rowptr[row + 1];
  float ax = 0.f, ay = 0.f;
  int e = e0;
  for (; e + 4 <= e1; e += 4) {
    int s0 = adj[e], s1 = adj[e + 1], s2 = adj[e + 2], s3 = adj[e + 3];
    unsigned int v0 = *(const unsigned int*)(feat + ((size_t)s0 << 7) + lane * 2);
    unsigned int v1 = *(const unsigned int*)(feat + ((size_t)s1 << 7) + lane * 2);
    unsigned int v2 = *(const unsigned int*)(feat + ((size_t)s2 << 7) + lane * 2);
    unsigned int v3 = *(const unsigned int*)(feat + ((size_t)s3 << 7) + lane * 2);
    ax += (bf2f_lo(v0) + bf2f_lo(v1)) + (bf2f_lo(v2) + bf2f_lo(v3));
    ay += (bf2f_hi(v0) + bf2f_hi(v1)) + (bf2f_hi(v2) + bf2f_hi(v3));
  }
  for (; e < e1; ++e) {
    unsigned int v0 = *(const unsigned int*)(feat + ((size_t)adj[e] << 7) + lane * 2);
    ax += bf2f_lo(v0);
    ay += bf2f_hi(v0);
  }
  float inv = 1.0f / fmaxf((float)(e1 - e0), 1.0f);
  int c0 = lane * 2, c1 = c0 + 1;
  size_t base = (size_t)row * 128;
  unsigned int rv = *(const unsigned int*)(hres + base + c0);
  float a0 = ax * inv + b1l[c0] + bf2f_lo(rv);
  float a1 = ay * inv + b1l[c1] + bf2f_hi(rv);
  float s = a0 + a1;
#pragma unroll
  for (int m = 32; m >= 1; m >>= 1) s += __shfl_xor(s, m);
  float mu = s * (1.0f / 128.0f);
  float d0 = a0 - mu, d1 = a1 - mu;
  float v = d0 * d0 + d1 * d1;
#pragma unroll
  for (int m = 32; m >= 1; m >>= 1) v += __shfl_xor(v, m);
  float rstd = rsqrtf(v * (1.0f / 128.0f) + 1e-5f);
  float h0 = fmaxf(d0 * rstd * g[c0] + b[c0], 0.0f);
  float h1 = fmaxf(d1 * rstd * g[c1] + b[c1], 0.0f);
  unsigned int hv = (unsigned int)f2bf(h0) | ((unsigned int)f2bf(h1) << 16);
  *(unsigned int*)(hres + base + c0) = hv;
}

// ---------------------------------------------------------------------------
// Layer-2 gather + epilogue: out = l2norm(mean_agg(z2) + b2l + r2), fp32 out.
// One wave per node; lane holds col lane (64 cols, bf16 feat).
// ---------------------------------------------------------------------------
__global__ __launch_bounds__(256) void gather_l2norm(
    const int* __restrict__ rowptr, const int* __restrict__ adj,
    const unsigned short* __restrict__ z2, const unsigned short* __restrict__ r2,
    const float* __restrict__ b2l, float* __restrict__ out) {
  int row = blockIdx.x * 4 + (threadIdx.x >> 6);
  if (row >= NNODES) return;
  int lane = threadIdx.x & 63;
  int e0 = rowptr[row], e1 = rowptr[row + 1];
  float acc = 0.f;
  int e = e0;
  for (; e + 4 <= e1; e += 4) {
    int s0 = adj[e], s1 = adj[e + 1], s2 = adj[e + 2], s3 = adj[e + 3];
    float v0 = bf2f(z2[((size_t)s0 << 6) + lane]);
    float v1 = bf2f(z2[((size_t)s1 << 6) + lane]);
    float v2 = bf2f(z2[((size_t)s2 << 6) + lane]);
    float v3 = bf2f(z2[((size_t)s3 << 6) + lane]);
    acc += (v0 + v1) + (v2 + v3);
  }
  for (; e < e1; ++e) acc += bf2f(z2[((size_t)adj[e] << 6) + lane]);
  float inv = 1.0f / fmaxf((float)(e1 - e0), 1.0f);
  size_t base = (size_t)row * 64;
  float val = acc * inv + b2l[lane] + bf2f(r2[base + lane]);
  float s = val * val;
#pragma unroll
  for (int m = 32; m >= 1; m >>= 1) s += __shfl_xor(s, m);
  float nrm = fmaxf(sqrtf(s), 1e-12f);
  out[base + lane] = val / nrm;
}

extern "C" void kernel_launch(void* const* d_in, const int* in_sizes, int n_in,
                              void* d_out, int out_size, void* d_ws, size_t ws_size,
                              hipStream_t stream) {
  const float* x   = (const float*)d_in[0];
  const int*   ei  = (const int*)d_in[1];
  const float* W1l = (const float*)d_in[2];
  const float* b1l = (const float*)d_in[3];
  const float* W1r = (const float*)d_in[4];
  const float* lng = (const float*)d_in[5];
  const float* lnb = (const float*)d_in[6];
  const float* W2l = (const float*)d_in[7];
  const float* b2l = (const float*)d_in[8];
  const float* W2r = (const float*)d_in[9];
  float* out = (float*)d_out;

  const int N = NNODES, E = NEDGES;

  // Workspace (shorts then ints), ~84 MB total.
  unsigned short* y1b = (unsigned short*)d_ws;      // N*128 (feat layer 1)
  unsigned short* r1b = y1b + (size_t)N * 128;      // N*128 (r1, then h)
  unsigned short* z2b = r1b + (size_t)N * 128;      // N*64
  unsigned short* r2b = z2b + (size_t)N * 64;       // N*64
  short* bswz1 = (short*)(r2b + (size_t)N * 64);    // 32768
  short* bswz2 = bswz1 + 32768;                     // 16384
  int* rowptr = (int*)(bswz2 + 16384);              // N+1
  int* cursor = rowptr + (N + 1);                   // N
  int* adj    = cursor + N;                         // E
  int* bsums  = adj + E;                            // NB_SCAN

  hipMemsetAsync(cursor, 0, (size_t)N * sizeof(int), stream);

  // CSR build (int atomics only)
  count_kernel<<<4096, 256, 0, stream>>>(ei, cursor);
  scan_a<<<NB_SCAN, 256, 0, stream>>>(cursor, rowptr, bsums);
  scan_b<<<1, 512, 0, stream>>>(bsums);
  scan_c<<<NB_SCAN, 256, 0, stream>>>(rowptr, cursor, bsums);
  fill_kernel<<<4096, 256, 0, stream>>>(ei, cursor, adj);

  // Weight prep (bf16, fragment-contiguous)
  prep_b<<<128, 256, 0, stream>>>(W1l, W1r, bswz1, 128);
  prep_b<<<64, 256, 0, stream>>>(W2l, W2r, bswz2, 64);

  const int gemm_blocks = (N + 63) / 64;  // 1563
  const int node_blocks = (N + 3) / 4;    // 25000

  // Layer 1: [y1|r1] = x @ [W1l|W1r] (MFMA); pull-aggregate y1 per dst;
  // fused mean+bias+residual+LN+ReLU -> h (in place over r1).
  gemm_mfma<256, false><<<gemm_blocks, 256, 0, stream>>>(x, bswz1, y1b, r1b, N);
  gather_ln_relu<<<node_blocks, 256, 0, stream>>>(rowptr, adj, y1b, r1b, b1l, lng, lnb);

  // Layer 2: [z2|r2] = h @ [W2l|W2r]; pull-aggregate z2; fused
  // mean+bias+residual+L2norm -> out (fp32).
  gemm_mfma<128, true><<<gemm_blocks, 256, 0, stream>>>(r1b, bswz2, z2b, r2b, N);
  gather_l2norm<<<node_blocks, 256, 0, stream>>>(rowptr, adj, z2b, r2b, b2l, out);
}

// Round 4
// 279.735 us; speedup vs baseline: 15.6126x; 1.4593x over previous
//
#include <hip/hip_runtime.h>
#include <hip/hip_bf16.h>

#define NNODES 100000
#define NEDGES 1600000
#define NBUCK 391        // ceil(NNODES / 256), 256 nodes per bucket
#define BUCK_SHIFT 8
#define NBLK_A 782       // ceil(NEDGES / 2048)

typedef short short8 __attribute__((ext_vector_type(8)));
typedef float floatx4 __attribute__((ext_vector_type(4)));

__device__ inline float bf2f_lo(unsigned int v) {
  union { unsigned int i; float f; } u; u.i = v << 16; return u.f;
}
__device__ inline float bf2f_hi(unsigned int v) {
  union { unsigned int i; float f; } u; u.i = v & 0xffff0000u; return u.f;
}
__device__ inline float bf2f(unsigned short s) {
  union { unsigned int i; float f; } u; u.i = ((unsigned int)s) << 16; return u.f;
}
__device__ inline unsigned short f2bf(float f) {  // RNE
  union { float f; unsigned int i; } u; u.f = f;
  unsigned int r = u.i + 0x7fffu + ((u.i >> 16) & 1u);
  return (unsigned short)(r >> 16);
}

// ---------------------------------------------------------------------------
// Weight prep: Bcat = [Wl | Wr] (128 x 2*half) cast to bf16, fragment-
// contiguous for the GEMM's B-panel register loads.
// ---------------------------------------------------------------------------
__global__ __launch_bounds__(256) void prep_b(const float* __restrict__ Wl,
                                              const float* __restrict__ Wr,
                                              short* __restrict__ Bswz, int half) {
  int total = 128 * 2 * half;
  int stride = gridDim.x * 256;
  for (int i = blockIdx.x * 256 + threadIdx.x; i < total; i += stride) {
    int j = i & 7;
    int lane = (i >> 3) & 63;
    int f = i >> 9;  // frag id = ct*4 + ks
    int ks = f & 3, ct = f >> 2;
    int k = ks * 32 + ((lane >> 4) << 3) + j;
    int c = ct * 16 + (lane & 15);
    float v = (c < half) ? Wl[k * half + c] : Wr[k * half + (c - half)];
    Bswz[i] = (short)f2bf(v);
  }
}

// ---------------------------------------------------------------------------
// MFMA GEMM: C = A @ Bcat, A: nrows x 128 (fp32 or bf16), Bcat: 128 x NCOLS.
// 4 waves, 64 rows/block; swapped operands -> packed bf16 ushort4 stores.
// ---------------------------------------------------------------------------
template <int NCOLS, bool ABF16>
__global__ __launch_bounds__(256) void gemm_mfma(
    const void* __restrict__ Av, const short* __restrict__ Bswz,
    unsigned short* __restrict__ outL, unsigned short* __restrict__ outR,
    int nrows) {
  constexpr int PW = NCOLS / 4;
  constexpr int CT = PW / 16;
  constexpr int HALF = NCOLS / 2;
  __shared__ unsigned short At[64][136];

  const int tid = threadIdx.x;
  const int lane = tid & 63;
  const int wave = tid >> 6;
  const int row0 = blockIdx.x * 64;

  if (ABF16) {
    const unsigned short* A = (const unsigned short*)Av;
    for (int i = tid; i < 64 * 16; i += 256) {
      int r = i >> 4, c8 = (i & 15) << 3;
      int gr = row0 + r;
      uint4 v = make_uint4(0, 0, 0, 0);
      if (gr < nrows) v = *(const uint4*)(A + (size_t)gr * 128 + c8);
      *(uint4*)&At[r][c8] = v;
    }
  } else {
    const float* A = (const float*)Av;
    for (int i = tid; i < 64 * 32; i += 256) {
      int r = i >> 5, c4 = (i & 31) << 2;
      int gr = row0 + r;
      float4 v = make_float4(0.f, 0.f, 0.f, 0.f);
      if (gr < nrows) v = *(const float4*)(A + (size_t)gr * 128 + c4);
      ushort4 u = make_ushort4(f2bf(v.x), f2bf(v.y), f2bf(v.z), f2bf(v.w));
      *(ushort4*)&At[r][c4] = u;
    }
  }
  __syncthreads();

  short8 bfrag[CT][4];
#pragma unroll
  for (int ct = 0; ct < CT; ++ct)
#pragma unroll
    for (int ks = 0; ks < 4; ++ks)
      bfrag[ct][ks] =
          *(const short8*)(Bswz + ((((wave * CT + ct) * 4 + ks) * 64 + lane) << 3));

  floatx4 acc[4][CT];
#pragma unroll
  for (int rt = 0; rt < 4; ++rt)
#pragma unroll
    for (int ct = 0; ct < CT; ++ct) acc[rt][ct] = (floatx4)(0.f);

#pragma unroll
  for (int rt = 0; rt < 4; ++rt) {
#pragma unroll
    for (int ks = 0; ks < 4; ++ks) {
      short8 af = *(const short8*)&At[rt * 16 + (lane & 15)][ks * 32 + ((lane >> 4) << 3)];
#pragma unroll
      for (int ct = 0; ct < CT; ++ct)
        acc[rt][ct] = __builtin_amdgcn_mfma_f32_16x16x32_bf16(
            bfrag[ct][ks], af, acc[rt][ct], 0, 0, 0);
    }
  }

#pragma unroll
  for (int rt = 0; rt < 4; ++rt) {
    int gr = row0 + rt * 16 + (lane & 15);
    if (gr >= nrows) continue;
#pragma unroll
    for (int ct = 0; ct < CT; ++ct) {
      int col = wave * PW + ct * 16 + ((lane >> 4) << 2);
      unsigned short* buf = (col < HALF) ? outL : outR;  // wave-uniform
      int c = col & (HALF - 1);
      floatx4 a = acc[rt][ct];
      ushort4 u = make_ushort4(f2bf(a[0]), f2bf(a[1]), f2bf(a[2]), f2bf(a[3]));
      *(ushort4*)(buf + (size_t)gr * HALF + c) = u;
    }
  }
}

// ---------------------------------------------------------------------------
// CSR build via bucketed counting sort (bucket = 256 consecutive dst nodes).
// Kills the random-scatter write amplification of atomic fill.
// ---------------------------------------------------------------------------
__global__ __launch_bounds__(256) void bucket_count(const int* __restrict__ dsts,
                                                    int* __restrict__ bcnt) {
  __shared__ int h[NBUCK];
  for (int i = threadIdx.x; i < NBUCK; i += 256) h[i] = 0;
  __syncthreads();
  int e0 = blockIdx.x * 2048;
  int eend = min(e0 + 2048, NEDGES);
  for (int e = e0 + threadIdx.x; e < eend; e += 256)
    atomicAdd(&h[dsts[e] >> BUCK_SHIFT], 1);
  __syncthreads();
  for (int i = threadIdx.x; i < NBUCK; i += 256)
    if (h[i]) atomicAdd(&bcnt[i], h[i]);
}

__global__ __launch_bounds__(512) void bucket_scan(const int* __restrict__ bcnt,
                                                   int* __restrict__ bexcl,
                                                   int* __restrict__ bcur) {
  __shared__ int sm[512];
  int t = threadIdx.x;
  int v = (t < NBUCK) ? bcnt[t] : 0;
  int acc = v;
  sm[t] = acc;
  __syncthreads();
  for (int off = 1; off < 512; off <<= 1) {
    int add = (t >= off) ? sm[t - off] : 0;
    __syncthreads();
    acc += add;
    sm[t] = acc;
    __syncthreads();
  }
  if (t < NBUCK) {
    bexcl[t] = acc - v;
    bcur[t] = acc - v;
  }
  if (t == 0) bexcl[NBUCK] = NEDGES;
}

// Partition edges into bucket-contiguous regions, packed src | (ldst<<24).
__global__ __launch_bounds__(256) void bucket_partition(
    const int* __restrict__ ei, int* __restrict__ bcur,
    unsigned int* __restrict__ part) {
  __shared__ int h[NBUCK];  // local hist, then block base per bucket
  __shared__ int r[NBUCK];  // rank counters
  for (int i = threadIdx.x; i < NBUCK; i += 256) { h[i] = 0; r[i] = 0; }
  __syncthreads();
  int e0 = blockIdx.x * 2048;
  int eend = min(e0 + 2048, NEDGES);
  for (int e = e0 + threadIdx.x; e < eend; e += 256)
    atomicAdd(&h[ei[NEDGES + e] >> BUCK_SHIFT], 1);
  __syncthreads();
  for (int i = threadIdx.x; i < NBUCK; i += 256) {
    int c = h[i];
    h[i] = c ? atomicAdd(&bcur[i], c) : 0;  // reserve contiguous chunk
  }
  __syncthreads();
  for (int e = e0 + threadIdx.x; e < eend; e += 256) {  // L2-hot re-read
    int s = ei[e], d = ei[NEDGES + e];
    int b = d >> BUCK_SHIFT;
    int pos = h[b] + atomicAdd(&r[b], 1);
    part[pos] = (unsigned int)s | ((unsigned int)(d & 255) << 24);
  }
}

// Per bucket: local 256-node hist -> rowptr; place srcs into adj (writes
// confined to the bucket's own contiguous ~16KB region).
__global__ __launch_bounds__(256) void bucket_build(
    const unsigned int* __restrict__ part, const int* __restrict__ bexcl,
    int* __restrict__ rowptr, int* __restrict__ adj) {
  __shared__ int h[256], ex[256];
  int b = blockIdx.x;
  int t = threadIdx.x;
  int base = bexcl[b], end = bexcl[b + 1];
  h[t] = 0;
  __syncthreads();
  for (int i = base + t; i < end; i += 256)
    atomicAdd(&h[part[i] >> 24], 1);
  __syncthreads();
  int v = h[t];
  int acc = v;
  ex[t] = acc;
  __syncthreads();
  for (int off = 1; off < 256; off <<= 1) {
    int add = (t >= off) ? ex[t - off] : 0;
    __syncthreads();
    acc += add;
    ex[t] = acc;
    __syncthreads();
  }
  int excl = acc - v;
  int node = (b << BUCK_SHIFT) + t;
  if (node < NNODES) rowptr[node] = base + excl;
  if (b == 0 && t == 0) rowptr[NNODES] = NEDGES;
  h[t] = 0;
  ex[t] = excl;
  __syncthreads();
  for (int i = base + t; i < end; i += 256) {
    unsigned int p = part[i];
    int ld = p >> 24;
    int rank = atomicAdd(&h[ld], 1);
    adj[base + ex[ld] + rank] = (int)(p & 0xFFFFFFu);
  }
}

// ---------------------------------------------------------------------------
// Layer-1 gather + epilogue: h = relu(LN(mean_agg(y1) + b1l + r1)).
// One wave per node; lane holds cols {2l, 2l+1}. h overwrites r1 (bf16).
// ---------------------------------------------------------------------------
__global__ __launch_bounds__(256) void gather_ln_relu(
    const int* __restrict__ rowptr, const int* __restrict__ adj,
    const unsigned short* __restrict__ feat, unsigned short* __restrict__ hres,
    const float* __restrict__ b1l, const float* __restrict__ g,
    const float* __restrict__ b) {
  int row = blockIdx.x * 4 + (threadIdx.x >> 6);
  if (row >= NNODES) return;
  int lane = threadIdx.x & 63;
  int e0 = rowptr[row], e1 = rowptr[row + 1];
  float ax = 0.f, ay = 0.f;
  int e = e0;
  for (; e + 4 <= e1; e += 4) {
    int s0 = adj[e], s1 = adj[e + 1], s2 = adj[e + 2], s3 = adj[e + 3];
    unsigned int v0 = *(const unsigned int*)(feat + ((size_t)s0 << 7) + lane * 2);
    unsigned int v1 = *(const unsigned int*)(feat + ((size_t)s1 << 7) + lane * 2);
    unsigned int v2 = *(const unsigned int*)(feat + ((size_t)s2 << 7) + lane * 2);
    unsigned int v3 = *(const unsigned int*)(feat + ((size_t)s3 << 7) + lane * 2);
    ax += (bf2f_lo(v0) + bf2f_lo(v1)) + (bf2f_lo(v2) + bf2f_lo(v3));
    ay += (bf2f_hi(v0) + bf2f_hi(v1)) + (bf2f_hi(v2) + bf2f_hi(v3));
  }
  for (; e < e1; ++e) {
    unsigned int v0 = *(const unsigned int*)(feat + ((size_t)adj[e] << 7) + lane * 2);
    ax += bf2f_lo(v0);
    ay += bf2f_hi(v0);
  }
  float inv = 1.0f / fmaxf((float)(e1 - e0), 1.0f);
  int c0 = lane * 2, c1 = c0 + 1;
  size_t base = (size_t)row * 128;
  unsigned int rv = *(const unsigned int*)(hres + base + c0);
  float a0 = ax * inv + b1l[c0] + bf2f_lo(rv);
  float a1 = ay * inv + b1l[c1] + bf2f_hi(rv);
  float s = a0 + a1;
#pragma unroll
  for (int m = 32; m >= 1; m >>= 1) s += __shfl_xor(s, m);
  float mu = s * (1.0f / 128.0f);
  float d0 = a0 - mu, d1 = a1 - mu;
  float v = d0 * d0 + d1 * d1;
#pragma unroll
  for (int m = 32; m >= 1; m >>= 1) v += __shfl_xor(v, m);
  float rstd = rsqrtf(v * (1.0f / 128.0f) + 1e-5f);
  float h0 = fmaxf(d0 * rstd * g[c0] + b[c0], 0.0f);
  float h1 = fmaxf(d1 * rstd * g[c1] + b[c1], 0.0f);
  unsigned int hv = (unsigned int)f2bf(h0) | ((unsigned int)f2bf(h1) << 16);
  *(unsigned int*)(hres + base + c0) = hv;
}

// ---------------------------------------------------------------------------
// Layer-2 gather + epilogue: out = l2norm(mean_agg(z2) + b2l + r2), fp32 out.
// ---------------------------------------------------------------------------
__global__ __launch_bounds__(256) void gather_l2norm(
    const int* __restrict__ rowptr, const int* __restrict__ adj,
    const unsigned short* __restrict__ z2, const unsigned short* __restrict__ r2,
    const float* __restrict__ b2l, float* __restrict__ out) {
  int row = blockIdx.x * 4 + (threadIdx.x >> 6);
  if (row >= NNODES) return;
  int lane = threadIdx.x & 63;
  int e0 = rowptr[row], e1 = rowptr[row + 1];
  float acc = 0.f;
  int e = e0;
  for (; e + 4 <= e1; e += 4) {
    int s0 = adj[e], s1 = adj[e + 1], s2 = adj[e + 2], s3 = adj[e + 3];
    float v0 = bf2f(z2[((size_t)s0 << 6) + lane]);
    float v1 = bf2f(z2[((size_t)s1 << 6) + lane]);
    float v2 = bf2f(z2[((size_t)s2 << 6) + lane]);
    float v3 = bf2f(z2[((size_t)s3 << 6) + lane]);
    acc += (v0 + v1) + (v2 + v3);
  }
  for (; e < e1; ++e) acc += bf2f(z2[((size_t)adj[e] << 6) + lane]);
  float inv = 1.0f / fmaxf((float)(e1 - e0), 1.0f);
  size_t base = (size_t)row * 64;
  float val = acc * inv + b2l[lane] + bf2f(r2[base + lane]);
  float s = val * val;
#pragma unroll
  for (int m = 32; m >= 1; m >>= 1) s += __shfl_xor(s, m);
  float nrm = fmaxf(sqrtf(s), 1e-12f);
  out[base + lane] = val / nrm;
}

extern "C" void kernel_launch(void* const* d_in, const int* in_sizes, int n_in,
                              void* d_out, int out_size, void* d_ws, size_t ws_size,
                              hipStream_t stream) {
  const float* x   = (const float*)d_in[0];
  const int*   ei  = (const int*)d_in[1];
  const float* W1l = (const float*)d_in[2];
  const float* b1l = (const float*)d_in[3];
  const float* W1r = (const float*)d_in[4];
  const float* lng = (const float*)d_in[5];
  const float* lnb = (const float*)d_in[6];
  const float* W2l = (const float*)d_in[7];
  const float* b2l = (const float*)d_in[8];
  const float* W2r = (const float*)d_in[9];
  float* out = (float*)d_out;

  const int N = NNODES;

  // Workspace layout (~115 MB).
  unsigned short* y1b = (unsigned short*)d_ws;      // N*128
  unsigned short* r1b = y1b + (size_t)N * 128;      // N*128 (r1, then h)
  unsigned short* z2b = r1b + (size_t)N * 128;      // N*64
  unsigned short* r2b = z2b + (size_t)N * 64;       // N*64
  short* bswz1 = (short*)(r2b + (size_t)N * 64);    // 32768
  short* bswz2 = bswz1 + 32768;                     // 16384
  int* rowptr = (int*)(bswz2 + 16384);              // N+1
  int* adj    = rowptr + (N + 1);                   // E
  unsigned int* part = (unsigned int*)(adj + NEDGES);  // E
  int* bcnt  = (int*)(part + NEDGES);               // NBUCK
  int* bexcl = bcnt + NBUCK;                        // NBUCK+1
  int* bcur  = bexcl + NBUCK + 1;                   // NBUCK

  hipMemsetAsync(bcnt, 0, NBUCK * sizeof(int), stream);

  // CSR build: bucketed counting sort (no scattered-write amplification).
  bucket_count<<<NBLK_A, 256, 0, stream>>>(ei + NEDGES, bcnt);
  bucket_scan<<<1, 512, 0, stream>>>(bcnt, bexcl, bcur);
  bucket_partition<<<NBLK_A, 256, 0, stream>>>(ei, bcur, part);
  bucket_build<<<NBUCK, 256, 0, stream>>>(part, bexcl, rowptr, adj);

  // Weight prep (bf16, fragment-contiguous)
  prep_b<<<128, 256, 0, stream>>>(W1l, W1r, bswz1, 128);
  prep_b<<<64, 256, 0, stream>>>(W2l, W2r, bswz2, 64);

  const int gemm_blocks = (N + 63) / 64;  // 1563
  const int node_blocks = (N + 3) / 4;    // 25000

  // Layer 1: [y1|r1] = x @ [W1l|W1r]; pull-aggregate y1 per dst; fused
  // mean+bias+residual+LN+ReLU -> h (in place over r1).
  gemm_mfma<256, false><<<gemm_blocks, 256, 0, stream>>>(x, bswz1, y1b, r1b, N);
  gather_ln_relu<<<node_blocks, 256, 0, stream>>>(rowptr, adj, y1b, r1b, b1l, lng, lnb);

  // Layer 2: [z2|r2] = h @ [W2l|W2r]; pull-aggregate z2; fused
  // mean+bias+residual+L2norm -> out (fp32).
  gemm_mfma<128, true><<<gemm_blocks, 256, 0, stream>>>(r1b, bswz2, z2b, r2b, N);
  gather_l2norm<<<node_blocks, 256, 0, stream>>>(rowptr, adj, z2b, r2b, b2l, out);
}

// Round 5
// 258.373 us; speedup vs baseline: 16.9035x; 1.0827x over previous
//
#include <hip/hip_runtime.h>
#include <hip/hip_bf16.h>

#define NNODES 100000
#define NEDGES 1600000
#define NBUCK 391        // ceil(NNODES / 256), 256 nodes per bucket
#define BUCK_SHIFT 8
#define NBLK_A 782       // ceil(NEDGES / 2048)

typedef short short8 __attribute__((ext_vector_type(8)));
typedef float floatx4 __attribute__((ext_vector_type(4)));

__device__ inline float bf2f_lo(unsigned int v) {
  union { unsigned int i; float f; } u; u.i = v << 16; return u.f;
}
__device__ inline float bf2f_hi(unsigned int v) {
  union { unsigned int i; float f; } u; u.i = v & 0xffff0000u; return u.f;
}
__device__ inline unsigned short f2bf(float f) {  // RNE
  union { float f; unsigned int i; } u; u.f = f;
  unsigned int r = u.i + 0x7fffu + ((u.i >> 16) & 1u);
  return (unsigned short)(r >> 16);
}

// ---------------------------------------------------------------------------
// Weight prep: Bcat = [Wl | Wr] (128 x 2*half) cast to bf16, fragment-
// contiguous for the GEMM's B-panel register loads.
// ---------------------------------------------------------------------------
__global__ __launch_bounds__(256) void prep_b(const float* __restrict__ Wl,
                                              const float* __restrict__ Wr,
                                              short* __restrict__ Bswz, int half) {
  int total = 128 * 2 * half;
  int stride = gridDim.x * 256;
  for (int i = blockIdx.x * 256 + threadIdx.x; i < total; i += stride) {
    int j = i & 7;
    int lane = (i >> 3) & 63;
    int f = i >> 9;  // frag id = ct*4 + ks
    int ks = f & 3, ct = f >> 2;
    int k = ks * 32 + ((lane >> 4) << 3) + j;
    int c = ct * 16 + (lane & 15);
    float v = (c < half) ? Wl[k * half + c] : Wr[k * half + (c - half)];
    Bswz[i] = (short)f2bf(v);
  }
}

// ---------------------------------------------------------------------------
// MFMA GEMM: C = A @ Bcat, A: nrows x 128 (fp32 or bf16), Bcat: 128 x NCOLS.
// 4 waves, 64 rows/block; swapped operands -> packed bf16 ushort4 stores.
// ---------------------------------------------------------------------------
template <int NCOLS, bool ABF16>
__global__ __launch_bounds__(256) void gemm_mfma(
    const void* __restrict__ Av, const short* __restrict__ Bswz,
    unsigned short* __restrict__ outL, unsigned short* __restrict__ outR,
    int nrows) {
  constexpr int PW = NCOLS / 4;
  constexpr int CT = PW / 16;
  constexpr int HALF = NCOLS / 2;
  __shared__ unsigned short At[64][136];

  const int tid = threadIdx.x;
  const int lane = tid & 63;
  const int wave = tid >> 6;
  const int row0 = blockIdx.x * 64;

  if (ABF16) {
    const unsigned short* A = (const unsigned short*)Av;
    for (int i = tid; i < 64 * 16; i += 256) {
      int r = i >> 4, c8 = (i & 15) << 3;
      int gr = row0 + r;
      uint4 v = make_uint4(0, 0, 0, 0);
      if (gr < nrows) v = *(const uint4*)(A + (size_t)gr * 128 + c8);
      *(uint4*)&At[r][c8] = v;
    }
  } else {
    const float* A = (const float*)Av;
    for (int i = tid; i < 64 * 32; i += 256) {
      int r = i >> 5, c4 = (i & 31) << 2;
      int gr = row0 + r;
      float4 v = make_float4(0.f, 0.f, 0.f, 0.f);
      if (gr < nrows) v = *(const float4*)(A + (size_t)gr * 128 + c4);
      ushort4 u = make_ushort4(f2bf(v.x), f2bf(v.y), f2bf(v.z), f2bf(v.w));
      *(ushort4*)&At[r][c4] = u;
    }
  }
  __syncthreads();

  short8 bfrag[CT][4];
#pragma unroll
  for (int ct = 0; ct < CT; ++ct)
#pragma unroll
    for (int ks = 0; ks < 4; ++ks)
      bfrag[ct][ks] =
          *(const short8*)(Bswz + ((((wave * CT + ct) * 4 + ks) * 64 + lane) << 3));

  floatx4 acc[4][CT];
#pragma unroll
  for (int rt = 0; rt < 4; ++rt)
#pragma unroll
    for (int ct = 0; ct < CT; ++ct) acc[rt][ct] = (floatx4)(0.f);

#pragma unroll
  for (int rt = 0; rt < 4; ++rt) {
#pragma unroll
    for (int ks = 0; ks < 4; ++ks) {
      short8 af = *(const short8*)&At[rt * 16 + (lane & 15)][ks * 32 + ((lane >> 4) << 3)];
#pragma unroll
      for (int ct = 0; ct < CT; ++ct)
        acc[rt][ct] = __builtin_amdgcn_mfma_f32_16x16x32_bf16(
            bfrag[ct][ks], af, acc[rt][ct], 0, 0, 0);
    }
  }

#pragma unroll
  for (int rt = 0; rt < 4; ++rt) {
    int gr = row0 + rt * 16 + (lane & 15);
    if (gr >= nrows) continue;
#pragma unroll
    for (int ct = 0; ct < CT; ++ct) {
      int col = wave * PW + ct * 16 + ((lane >> 4) << 2);
      unsigned short* buf = (col < HALF) ? outL : outR;  // wave-uniform
      int c = col & (HALF - 1);
      floatx4 a = acc[rt][ct];
      ushort4 u = make_ushort4(f2bf(a[0]), f2bf(a[1]), f2bf(a[2]), f2bf(a[3]));
      *(ushort4*)(buf + (size_t)gr * HALF + c) = u;
    }
  }
}

// ---------------------------------------------------------------------------
// CSR build via bucketed counting sort (bucket = 256 consecutive dst nodes).
// ---------------------------------------------------------------------------
__global__ __launch_bounds__(256) void bucket_count(const int* __restrict__ dsts,
                                                    int* __restrict__ bcnt) {
  __shared__ int h[NBUCK];
  for (int i = threadIdx.x; i < NBUCK; i += 256) h[i] = 0;
  __syncthreads();
  int e0 = blockIdx.x * 2048;
  int eend = min(e0 + 2048, NEDGES);
  for (int e = e0 + threadIdx.x; e < eend; e += 256)
    atomicAdd(&h[dsts[e] >> BUCK_SHIFT], 1);
  __syncthreads();
  for (int i = threadIdx.x; i < NBUCK; i += 256)
    if (h[i]) atomicAdd(&bcnt[i], h[i]);
}

__global__ __launch_bounds__(512) void bucket_scan(const int* __restrict__ bcnt,
                                                   int* __restrict__ bexcl,
                                                   int* __restrict__ bcur) {
  __shared__ int sm[512];
  int t = threadIdx.x;
  int v = (t < NBUCK) ? bcnt[t] : 0;
  int acc = v;
  sm[t] = acc;
  __syncthreads();
  for (int off = 1; off < 512; off <<= 1) {
    int add = (t >= off) ? sm[t - off] : 0;
    __syncthreads();
    acc += add;
    sm[t] = acc;
    __syncthreads();
  }
  if (t < NBUCK) {
    bexcl[t] = acc - v;
    bcur[t] = acc - v;
  }
  if (t == 0) bexcl[NBUCK] = NEDGES;
}

// Partition edges into bucket-contiguous regions, packed src | (ldst<<24).
__global__ __launch_bounds__(256) void bucket_partition(
    const int* __restrict__ ei, int* __restrict__ bcur,
    unsigned int* __restrict__ part) {
  __shared__ int h[NBUCK];
  __shared__ int r[NBUCK];
  for (int i = threadIdx.x; i < NBUCK; i += 256) { h[i] = 0; r[i] = 0; }
  __syncthreads();
  int e0 = blockIdx.x * 2048;
  int eend = min(e0 + 2048, NEDGES);
  for (int e = e0 + threadIdx.x; e < eend; e += 256)
    atomicAdd(&h[ei[NEDGES + e] >> BUCK_SHIFT], 1);
  __syncthreads();
  for (int i = threadIdx.x; i < NBUCK; i += 256) {
    int c = h[i];
    h[i] = c ? atomicAdd(&bcur[i], c) : 0;
  }
  __syncthreads();
  for (int e = e0 + threadIdx.x; e < eend; e += 256) {
    int s = ei[e], d = ei[NEDGES + e];
    int b = d >> BUCK_SHIFT;
    int pos = h[b] + atomicAdd(&r[b], 1);
    part[pos] = (unsigned int)s | ((unsigned int)(d & 255) << 24);
  }
}

__global__ __launch_bounds__(256) void bucket_build(
    const unsigned int* __restrict__ part, const int* __restrict__ bexcl,
    int* __restrict__ rowptr, int* __restrict__ adj) {
  __shared__ int h[256], ex[256];
  int b = blockIdx.x;
  int t = threadIdx.x;
  int base = bexcl[b], end = bexcl[b + 1];
  h[t] = 0;
  __syncthreads();
  for (int i = base + t; i < end; i += 256)
    atomicAdd(&h[part[i] >> 24], 1);
  __syncthreads();
  int v = h[t];
  int acc = v;
  ex[t] = acc;
  __syncthreads();
  for (int off = 1; off < 256; off <<= 1) {
    int add = (t >= off) ? ex[t - off] : 0;
    __syncthreads();
    acc += add;
    ex[t] = acc;
    __syncthreads();
  }
  int excl = acc - v;
  int node = (b << BUCK_SHIFT) + t;
  if (node < NNODES) rowptr[node] = base + excl;
  if (b == 0 && t == 0) rowptr[NNODES] = NEDGES;
  h[t] = 0;
  ex[t] = excl;
  __syncthreads();
  for (int i = base + t; i < end; i += 256) {
    unsigned int p = part[i];
    int ld = p >> 24;
    int rank = atomicAdd(&h[ld], 1);
    adj[base + ex[ld] + rank] = (int)(p & 0xFFFFFFu);
  }
}

// ---------------------------------------------------------------------------
// Layer-1 gather + epilogue: h = relu(LN(mean_agg(y1) + b1l + r1)).
// One wave per node. Lane = (eh, cg): eh = lane>>5 picks 1 of 2 edges per
// wave-load; cg = lane&31 picks 4 consecutive cols (uint2 = 4 bf16).
// Halves combined via shfl_xor(32); LN reduce over duplicated halves (/256).
// h overwrites r1 in place (bf16), written by eh==0 half only.
// ---------------------------------------------------------------------------
__global__ __launch_bounds__(256) void gather_ln_relu(
    const int* __restrict__ rowptr, const int* __restrict__ adj,
    const unsigned short* __restrict__ feat, unsigned short* __restrict__ hres,
    const float* __restrict__ b1l, const float* __restrict__ g,
    const float* __restrict__ b) {
  int row = blockIdx.x * 4 + (threadIdx.x >> 6);
  if (row >= NNODES) return;
  int lane = threadIdx.x & 63;
  int eh = lane >> 5;       // edge slot within pair
  int cg = lane & 31;       // col group: cols 4cg..4cg+3
  int e0 = rowptr[row], e1 = rowptr[row + 1];
  float a0 = 0.f, a1 = 0.f, a2 = 0.f, a3 = 0.f;
  int e = e0;
  for (; e + 8 <= e1; e += 8) {
    int s0 = adj[e + eh], s1 = adj[e + 2 + eh];
    int s2 = adj[e + 4 + eh], s3 = adj[e + 6 + eh];
    uint2 v0 = *(const uint2*)(feat + ((size_t)s0 << 7) + (cg << 2));
    uint2 v1 = *(const uint2*)(feat + ((size_t)s1 << 7) + (cg << 2));
    uint2 v2 = *(const uint2*)(feat + ((size_t)s2 << 7) + (cg << 2));
    uint2 v3 = *(const uint2*)(feat + ((size_t)s3 << 7) + (cg << 2));
    a0 += (bf2f_lo(v0.x) + bf2f_lo(v1.x)) + (bf2f_lo(v2.x) + bf2f_lo(v3.x));
    a1 += (bf2f_hi(v0.x) + bf2f_hi(v1.x)) + (bf2f_hi(v2.x) + bf2f_hi(v3.x));
    a2 += (bf2f_lo(v0.y) + bf2f_lo(v1.y)) + (bf2f_lo(v2.y) + bf2f_lo(v3.y));
    a3 += (bf2f_hi(v0.y) + bf2f_hi(v1.y)) + (bf2f_hi(v2.y) + bf2f_hi(v3.y));
  }
  for (; e + 2 <= e1; e += 2) {
    int s0 = adj[e + eh];
    uint2 v0 = *(const uint2*)(feat + ((size_t)s0 << 7) + (cg << 2));
    a0 += bf2f_lo(v0.x);
    a1 += bf2f_hi(v0.x);
    a2 += bf2f_lo(v0.y);
    a3 += bf2f_hi(v0.y);
  }
  if (e < e1 && eh == 0) {  // odd leftover edge, handled by half 0
    int s0 = adj[e];
    uint2 v0 = *(const uint2*)(feat + ((size_t)s0 << 7) + (cg << 2));
    a0 += bf2f_lo(v0.x);
    a1 += bf2f_hi(v0.x);
    a2 += bf2f_lo(v0.y);
    a3 += bf2f_hi(v0.y);
  }
  a0 += __shfl_xor(a0, 32);
  a1 += __shfl_xor(a1, 32);
  a2 += __shfl_xor(a2, 32);
  a3 += __shfl_xor(a3, 32);

  float inv = 1.0f / fmaxf((float)(e1 - e0), 1.0f);
  int c0 = cg << 2;
  size_t base = (size_t)row * 128;
  float4 bias = *(const float4*)(b1l + c0);
  uint2 rv = *(const uint2*)(hres + base + c0);
  a0 = a0 * inv + bias.x + bf2f_lo(rv.x);
  a1 = a1 * inv + bias.y + bf2f_hi(rv.x);
  a2 = a2 * inv + bias.z + bf2f_lo(rv.y);
  a3 = a3 * inv + bias.w + bf2f_hi(rv.y);
  float s = (a0 + a1) + (a2 + a3);
#pragma unroll
  for (int m = 32; m >= 1; m >>= 1) s += __shfl_xor(s, m);
  float mu = s * (1.0f / 256.0f);  // halves duplicated -> /256
  float d0 = a0 - mu, d1 = a1 - mu, d2 = a2 - mu, d3 = a3 - mu;
  float v = (d0 * d0 + d1 * d1) + (d2 * d2 + d3 * d3);
#pragma unroll
  for (int m = 32; m >= 1; m >>= 1) v += __shfl_xor(v, m);
  float rstd = rsqrtf(v * (1.0f / 256.0f) + 1e-5f);
  if (eh == 0) {
    float4 gg = *(const float4*)(g + c0);
    float4 bb = *(const float4*)(b + c0);
    float h0 = fmaxf(d0 * rstd * gg.x + bb.x, 0.0f);
    float h1 = fmaxf(d1 * rstd * gg.y + bb.y, 0.0f);
    float h2 = fmaxf(d2 * rstd * gg.z + bb.z, 0.0f);
    float h3 = fmaxf(d3 * rstd * gg.w + bb.w, 0.0f);
    uint2 hv;
    hv.x = (unsigned int)f2bf(h0) | ((unsigned int)f2bf(h1) << 16);
    hv.y = (unsigned int)f2bf(h2) | ((unsigned int)f2bf(h3) << 16);
    *(uint2*)(hres + base + c0) = hv;
  }
}

// ---------------------------------------------------------------------------
// Layer-2 gather + epilogue: out = l2norm(mean_agg(z2) + b2l + r2), fp32 out.
// One wave per node. eh = lane>>4 picks 1 of 4 edges per wave-load;
// cg = lane&15 picks 4 cols (uint2). Groups combined via shfl_xor(16,32);
// L2 reduce within each 16-lane group (complete row per group).
// ---------------------------------------------------------------------------
__global__ __launch_bounds__(256) void gather_l2norm(
    const int* __restrict__ rowptr, const int* __restrict__ adj,
    const unsigned short* __restrict__ z2, const unsigned short* __restrict__ r2,
    const float* __restrict__ b2l, float* __restrict__ out) {
  int row = blockIdx.x * 4 + (threadIdx.x >> 6);
  if (row >= NNODES) return;
  int lane = threadIdx.x & 63;
  int eh = lane >> 4;   // edge slot within quad
  int cg = lane & 15;   // col group: cols 4cg..4cg+3
  int e0 = rowptr[row], e1 = rowptr[row + 1];
  float a0 = 0.f, a1 = 0.f, a2 = 0.f, a3 = 0.f;
  int e = e0;
  for (; e + 8 <= e1; e += 8) {
    int s0 = adj[e + eh], s1 = adj[e + 4 + eh];
    uint2 v0 = *(const uint2*)(z2 + ((size_t)s0 << 6) + (cg << 2));
    uint2 v1 = *(const uint2*)(z2 + ((size_t)s1 << 6) + (cg << 2));
    a0 += bf2f_lo(v0.x) + bf2f_lo(v1.x);
    a1 += bf2f_hi(v0.x) + bf2f_hi(v1.x);
    a2 += bf2f_lo(v0.y) + bf2f_lo(v1.y);
    a3 += bf2f_hi(v0.y) + bf2f_hi(v1.y);
  }
  for (; e + 4 <= e1; e += 4) {
    int s0 = adj[e + eh];
    uint2 v0 = *(const uint2*)(z2 + ((size_t)s0 << 6) + (cg << 2));
    a0 += bf2f_lo(v0.x);
    a1 += bf2f_hi(v0.x);
    a2 += bf2f_lo(v0.y);
    a3 += bf2f_hi(v0.y);
  }
  int rem = e1 - e;
  if (eh < rem) {
    int s0 = adj[e + eh];
    uint2 v0 = *(const uint2*)(z2 + ((size_t)s0 << 6) + (cg << 2));
    a0 += bf2f_lo(v0.x);
    a1 += bf2f_hi(v0.x);
    a2 += bf2f_lo(v0.y);
    a3 += bf2f_hi(v0.y);
  }
  a0 += __shfl_xor(a0, 16); a0 += __shfl_xor(a0, 32);
  a1 += __shfl_xor(a1, 16); a1 += __shfl_xor(a1, 32);
  a2 += __shfl_xor(a2, 16); a2 += __shfl_xor(a2, 32);
  a3 += __shfl_xor(a3, 16); a3 += __shfl_xor(a3, 32);

  float inv = 1.0f / fmaxf((float)(e1 - e0), 1.0f);
  int c0 = cg << 2;
  size_t base = (size_t)row * 64;
  float4 bias = *(const float4*)(b2l + c0);
  uint2 rv = *(const uint2*)(r2 + base + c0);
  a0 = a0 * inv + bias.x + bf2f_lo(rv.x);
  a1 = a1 * inv + bias.y + bf2f_hi(rv.x);
  a2 = a2 * inv + bias.z + bf2f_lo(rv.y);
  a3 = a3 * inv + bias.w + bf2f_hi(rv.y);
  float s = (a0 * a0 + a1 * a1) + (a2 * a2 + a3 * a3);
#pragma unroll
  for (int m = 8; m >= 1; m >>= 1) s += __shfl_xor(s, m);  // within 16-lane grp
  float nrm = fmaxf(sqrtf(s), 1e-12f);
  if (eh == 0) {
    float4 o;
    o.x = a0 / nrm; o.y = a1 / nrm; o.z = a2 / nrm; o.w = a3 / nrm;
    *(float4*)(out + base + c0) = o;
  }
}

extern "C" void kernel_launch(void* const* d_in, const int* in_sizes, int n_in,
                              void* d_out, int out_size, void* d_ws, size_t ws_size,
                              hipStream_t stream) {
  const float* x   = (const float*)d_in[0];
  const int*   ei  = (const int*)d_in[1];
  const float* W1l = (const float*)d_in[2];
  const float* b1l = (const float*)d_in[3];
  const float* W1r = (const float*)d_in[4];
  const float* lng = (const float*)d_in[5];
  const float* lnb = (const float*)d_in[6];
  const float* W2l = (const float*)d_in[7];
  const float* b2l = (const float*)d_in[8];
  const float* W2r = (const float*)d_in[9];
  float* out = (float*)d_out;

  const int N = NNODES;

  unsigned short* y1b = (unsigned short*)d_ws;      // N*128
  unsigned short* r1b = y1b + (size_t)N * 128;      // N*128 (r1, then h)
  unsigned short* z2b = r1b + (size_t)N * 128;      // N*64
  unsigned short* r2b = z2b + (size_t)N * 64;       // N*64
  short* bswz1 = (short*)(r2b + (size_t)N * 64);    // 32768
  short* bswz2 = bswz1 + 32768;                     // 16384
  int* rowptr = (int*)(bswz2 + 16384);              // N+1
  int* adj    = rowptr + (N + 1);                   // E
  unsigned int* part = (unsigned int*)(adj + NEDGES);  // E
  int* bcnt  = (int*)(part + NEDGES);               // NBUCK
  int* bexcl = bcnt + NBUCK;                        // NBUCK+1
  int* bcur  = bexcl + NBUCK + 1;                   // NBUCK

  hipMemsetAsync(bcnt, 0, NBUCK * sizeof(int), stream);

  bucket_count<<<NBLK_A, 256, 0, stream>>>(ei + NEDGES, bcnt);
  bucket_scan<<<1, 512, 0, stream>>>(bcnt, bexcl, bcur);
  bucket_partition<<<NBLK_A, 256, 0, stream>>>(ei, bcur, part);
  bucket_build<<<NBUCK, 256, 0, stream>>>(part, bexcl, rowptr, adj);

  prep_b<<<128, 256, 0, stream>>>(W1l, W1r, bswz1, 128);
  prep_b<<<64, 256, 0, stream>>>(W2l, W2r, bswz2, 64);

  const int gemm_blocks = (N + 63) / 64;  // 1563
  const int node_blocks = (N + 3) / 4;    // 25000

  gemm_mfma<256, false><<<gemm_blocks, 256, 0, stream>>>(x, bswz1, y1b, r1b, N);
  gather_ln_relu<<<node_blocks, 256, 0, stream>>>(rowptr, adj, y1b, r1b, b1l, lng, lnb);

  gemm_mfma<128, true><<<gemm_blocks, 256, 0, stream>>>(r1b, bswz2, z2b, r2b, N);
  gather_l2norm<<<node_blocks, 256, 0, stream>>>(rowptr, adj, z2b, r2b, b2l, out);
}

// Round 8
// 226.784 us; speedup vs baseline: 19.2579x; 1.1393x over previous
//
#include <hip/hip_runtime.h>
#include <hip/hip_bf16.h>

#define NNODES 100000
#define NEDGES 1600000
#define NBUCK 391        // ceil(NNODES / 256), 256 nodes per bucket
#define BUCK_SHIFT 8
#define NBLK_A 782       // ceil(NEDGES / 2048)
#define GEMM_BLOCKS 1563 // ceil(NNODES / 64)

typedef short short8 __attribute__((ext_vector_type(8)));
typedef float floatx4 __attribute__((ext_vector_type(4)));

__device__ inline float bf2f_lo(unsigned int v) {
  union { unsigned int i; float f; } u; u.i = v << 16; return u.f;
}
__device__ inline float bf2f_hi(unsigned int v) {
  union { unsigned int i; float f; } u; u.i = v & 0xffff0000u; return u.f;
}
__device__ inline unsigned short f2bf(float f) {  // RNE
  union { float f; unsigned int i; } u; u.f = f;
  unsigned int r = u.i + 0x7fffu + ((u.i >> 16) & 1u);
  return (unsigned short)(r >> 16);
}

// ---------------------------------------------------------------------------
// Weight prep body: Bcat = [Wl | Wr] (128 x 2*half) -> bf16 fragment-
// contiguous layout for the GEMM's B-panel register loads.
// ---------------------------------------------------------------------------
__device__ void prep_body(int bid, int nblk, const float* __restrict__ Wl,
                          const float* __restrict__ Wr,
                          short* __restrict__ Bswz, int half) {
  int total = 128 * 2 * half;
  int stride = nblk * 256;
  for (int i = bid * 256 + threadIdx.x; i < total; i += stride) {
    int j = i & 7;
    int lane = (i >> 3) & 63;
    int f = i >> 9;  // frag id = ct*4 + ks
    int ks = f & 3, ct = f >> 2;
    int k = ks * 32 + ((lane >> 4) << 3) + j;
    int c = ct * 16 + (lane & 15);
    float v = (c < half) ? Wl[k * half + c] : Wr[k * half + (c - half)];
    Bswz[i] = (short)f2bf(v);
  }
}

// ---------------------------------------------------------------------------
// MFMA GEMM body: C = A @ Bcat, A: nrows x 128 (fp32 or bf16), Bcat: 128 x
// NCOLS. 4 waves, 64 rows/block; swapped operands -> lane owns 4 consecutive
// cols -> packed bf16 ushort4 stores. Cols < NCOLS/2 -> outL, else outR.
// ---------------------------------------------------------------------------
template <int NCOLS, bool ABF16>
__device__ void gemm_body(int bid, const void* __restrict__ Av,
                          const short* __restrict__ Bswz,
                          unsigned short* __restrict__ outL,
                          unsigned short* __restrict__ outR, int nrows) {
  constexpr int PW = NCOLS / 4;
  constexpr int CT = PW / 16;
  constexpr int HALF = NCOLS / 2;
  __shared__ unsigned short At[64][136];

  const int tid = threadIdx.x;
  const int lane = tid & 63;
  const int wave = tid >> 6;
  const int row0 = bid * 64;

  if (ABF16) {
    const unsigned short* A = (const unsigned short*)Av;
    for (int i = tid; i < 64 * 16; i += 256) {
      int r = i >> 4, c8 = (i & 15) << 3;
      int gr = row0 + r;
      uint4 v = make_uint4(0, 0, 0, 0);
      if (gr < nrows) v = *(const uint4*)(A + (size_t)gr * 128 + c8);
      *(uint4*)&At[r][c8] = v;
    }
  } else {
    const float* A = (const float*)Av;
    for (int i = tid; i < 64 * 32; i += 256) {
      int r = i >> 5, c4 = (i & 31) << 2;
      int gr = row0 + r;
      float4 v = make_float4(0.f, 0.f, 0.f, 0.f);
      if (gr < nrows) v = *(const float4*)(A + (size_t)gr * 128 + c4);
      ushort4 u = make_ushort4(f2bf(v.x), f2bf(v.y), f2bf(v.z), f2bf(v.w));
      *(ushort4*)&At[r][c4] = u;
    }
  }
  __syncthreads();

  short8 bfrag[CT][4];
#pragma unroll
  for (int ct = 0; ct < CT; ++ct)
#pragma unroll
    for (int ks = 0; ks < 4; ++ks)
      bfrag[ct][ks] =
          *(const short8*)(Bswz + ((((wave * CT + ct) * 4 + ks) * 64 + lane) << 3));

  floatx4 acc[4][CT];
#pragma unroll
  for (int rt = 0; rt < 4; ++rt)
#pragma unroll
    for (int ct = 0; ct < CT; ++ct) acc[rt][ct] = (floatx4)(0.f);

#pragma unroll
  for (int rt = 0; rt < 4; ++rt) {
#pragma unroll
    for (int ks = 0; ks < 4; ++ks) {
      short8 af = *(const short8*)&At[rt * 16 + (lane & 15)][ks * 32 + ((lane >> 4) << 3)];
#pragma unroll
      for (int ct = 0; ct < CT; ++ct)
        acc[rt][ct] = __builtin_amdgcn_mfma_f32_16x16x32_bf16(
            bfrag[ct][ks], af, acc[rt][ct], 0, 0, 0);
    }
  }

#pragma unroll
  for (int rt = 0; rt < 4; ++rt) {
    int gr = row0 + rt * 16 + (lane & 15);
    if (gr >= nrows) continue;
#pragma unroll
    for (int ct = 0; ct < CT; ++ct) {
      int col = wave * PW + ct * 16 + ((lane >> 4) << 2);
      unsigned short* buf = (col < HALF) ? outL : outR;  // wave-uniform
      int c = col & (HALF - 1);
      floatx4 a = acc[rt][ct];
      ushort4 u = make_ushort4(f2bf(a[0]), f2bf(a[1]), f2bf(a[2]), f2bf(a[3]));
      *(ushort4*)(buf + (size_t)gr * HALF + c) = u;
    }
  }
}

// ---------------------------------------------------------------------------
// CSR build bodies (bucketed counting sort).
// ---------------------------------------------------------------------------
__device__ void count_body(int bid, const int* __restrict__ dsts,
                           int* __restrict__ bcnt) {
  __shared__ int h[NBUCK];
  for (int i = threadIdx.x; i < NBUCK; i += 256) h[i] = 0;
  __syncthreads();
  int e0 = bid * 2048;
  int eend = min(e0 + 2048, NEDGES);
  for (int e = e0 + threadIdx.x; e < eend; e += 256)
    atomicAdd(&h[dsts[e] >> BUCK_SHIFT], 1);
  __syncthreads();
  for (int i = threadIdx.x; i < NBUCK; i += 256)
    if (h[i]) atomicAdd(&bcnt[i], h[i]);
}

__device__ void partition_body(int bid, const int* __restrict__ ei,
                               int* __restrict__ bcur,
                               unsigned int* __restrict__ part) {
  __shared__ int h[NBUCK];
  __shared__ int r[NBUCK];
  for (int i = threadIdx.x; i < NBUCK; i += 256) { h[i] = 0; r[i] = 0; }
  __syncthreads();
  int e0 = bid * 2048;
  int eend = min(e0 + 2048, NEDGES);
  for (int e = e0 + threadIdx.x; e < eend; e += 256)
    atomicAdd(&h[ei[NEDGES + e] >> BUCK_SHIFT], 1);
  __syncthreads();
  for (int i = threadIdx.x; i < NBUCK; i += 256) {
    int c = h[i];
    h[i] = c ? atomicAdd(&bcur[i], c) : 0;
  }
  __syncthreads();
  for (int e = e0 + threadIdx.x; e < eend; e += 256) {
    int s = ei[e], d = ei[NEDGES + e];
    int b = d >> BUCK_SHIFT;
    int pos = h[b] + atomicAdd(&r[b], 1);
    part[pos] = (unsigned int)s | ((unsigned int)(d & 255) << 24);
  }
}

// front1 = bucket_count (782) || prep_b W1 (128) || prep_b W2 (64)
__global__ __launch_bounds__(256) void front1(
    const int* __restrict__ ei, int* __restrict__ bcnt,
    const float* __restrict__ W1l, const float* __restrict__ W1r,
    short* __restrict__ bswz1, const float* __restrict__ W2l,
    const float* __restrict__ W2r, short* __restrict__ bswz2) {
  int bid = blockIdx.x;
  if (bid < NBLK_A) {
    count_body(bid, ei + NEDGES, bcnt);
  } else if (bid < NBLK_A + 128) {
    prep_body(bid - NBLK_A, 128, W1l, W1r, bswz1, 128);
  } else {
    prep_body(bid - NBLK_A - 128, 64, W2l, W2r, bswz2, 64);
  }
}

// front2 = GEMM1 (1563) || bucket_partition (782)
__global__ __launch_bounds__(256) void front2(
    const float* __restrict__ x, const short* __restrict__ bswz1,
    unsigned short* __restrict__ y1b, unsigned short* __restrict__ r1b,
    const int* __restrict__ ei, int* __restrict__ bcur,
    unsigned int* __restrict__ part) {
  int bid = blockIdx.x;
  if (bid < GEMM_BLOCKS) {
    gemm_body<256, false>(bid, x, bswz1, y1b, r1b, NNODES);
  } else {
    partition_body(bid - GEMM_BLOCKS, ei, bcur, part);
  }
}

__global__ __launch_bounds__(512) void bucket_scan(const int* __restrict__ bcnt,
                                                   int* __restrict__ bexcl,
                                                   int* __restrict__ bcur) {
  __shared__ int sm[512];
  int t = threadIdx.x;
  int v = (t < NBUCK) ? bcnt[t] : 0;
  int acc = v;
  sm[t] = acc;
  __syncthreads();
  for (int off = 1; off < 512; off <<= 1) {
    int add = (t >= off) ? sm[t - off] : 0;
    __syncthreads();
    acc += add;
    sm[t] = acc;
    __syncthreads();
  }
  if (t < NBUCK) {
    bexcl[t] = acc - v;
    bcur[t] = acc - v;
  }
  if (t == 0) bexcl[NBUCK] = NEDGES;
}

__global__ __launch_bounds__(256) void bucket_build(
    const unsigned int* __restrict__ part, const int* __restrict__ bexcl,
    int* __restrict__ rowptr, int* __restrict__ adj) {
  __shared__ int h[256], ex[256];
  int b = blockIdx.x;
  int t = threadIdx.x;
  int base = bexcl[b], end = bexcl[b + 1];
  h[t] = 0;
  __syncthreads();
  for (int i = base + t; i < end; i += 256)
    atomicAdd(&h[part[i] >> 24], 1);
  __syncthreads();
  int v = h[t];
  int acc = v;
  ex[t] = acc;
  __syncthreads();
  for (int off = 1; off < 256; off <<= 1) {
    int add = (t >= off) ? ex[t - off] : 0;
    __syncthreads();
    acc += add;
    ex[t] = acc;
    __syncthreads();
  }
  int excl = acc - v;
  int node = (b << BUCK_SHIFT) + t;
  if (node < NNODES) rowptr[node] = base + excl;
  if (b == 0 && t == 0) rowptr[NNODES] = NEDGES;
  h[t] = 0;
  ex[t] = excl;
  __syncthreads();
  for (int i = base + t; i < end; i += 256) {
    unsigned int p = part[i];
    int ld = p >> 24;
    int rank = atomicAdd(&h[ld], 1);
    adj[base + ex[ld] + rank] = (int)(p & 0xFFFFFFu);
  }
}

// ---------------------------------------------------------------------------
// Layer-1 gather + epilogue: h = relu(LN(mean_agg(y1) + b1l + r1)), bf16 feat.
// 2 rows per wave (lanes 0-31 row A, 32-63 row B). Per half: eh = 1-of-2
// edge-parity subgroup, cg = 1-of-16 col group (8 bf16 cols = uint4).
// SHFL SAFETY: lane l5 holds adj entry for chunk-edge (2*(l5&15) + l5>>4),
// so edge parity == holder's subgroup. The reader of edge j+2u+eh shfls from
// lane (eh<<4) + j/2 + u — same subgroup, identical guard -> the source lane
// is active whenever the reader is (fixes R6/R7's inactive-lane bpermute).
// h overwrites r1 in place (bf16). Requires NNODES % 8 == 0.
// ---------------------------------------------------------------------------
__global__ __launch_bounds__(256) void gather_ln_relu(
    const int* __restrict__ rowptr, const int* __restrict__ adj,
    const unsigned short* __restrict__ feat, unsigned short* __restrict__ hres,
    const float* __restrict__ b1l, const float* __restrict__ g,
    const float* __restrict__ b) {
  const int lane = threadIdx.x & 63;
  const int wave = threadIdx.x >> 6;
  const int half = lane >> 5;       // 0 = row A, 1 = row B
  const int l5 = lane & 31;
  const int eh = l5 >> 4;           // edge-parity subgroup
  const int cg = lane & 15;         // col group: 8 cols
  const int row = blockIdx.x * 8 + wave * 2 + half;
  const int cgo = cg << 3;          // element offset into 128-col row

  int e0 = rowptr[row], e1 = rowptr[row + 1];
  int deg = e1 - e0;
  float a0 = 0.f, a1 = 0.f, a2 = 0.f, a3 = 0.f;
  float a4 = 0.f, a5 = 0.f, a6 = 0.f, a7 = 0.f;

  for (int be = 0; be < deg; be += 32) {   // chunk of <=32 edges per row
    int chunk = min(deg - be, 32);
    int ledge = ((l5 & 15) << 1) + eh;     // parity-matched adj assignment
    int my = 0;
    if (ledge < chunk) my = adj[e0 + be + ledge];
#pragma unroll 1
    for (int j = 0; j < chunk; j += 16) {
#pragma unroll
      for (int u = 0; u < 8; ++u) {
        int s = __shfl(my, (half << 5) + (eh << 4) + ((j >> 1) + u));
        if (j + 2 * u + eh < chunk) {
          uint4 v = *(const uint4*)(feat + ((size_t)s << 7) + cgo);
          a0 += bf2f_lo(v.x); a1 += bf2f_hi(v.x);
          a2 += bf2f_lo(v.y); a3 += bf2f_hi(v.y);
          a4 += bf2f_lo(v.z); a5 += bf2f_hi(v.z);
          a6 += bf2f_lo(v.w); a7 += bf2f_hi(v.w);
        }
      }
    }
  }
  // combine the two parity subgroups (stays within each 32-lane half)
  a0 += __shfl_xor(a0, 16); a1 += __shfl_xor(a1, 16);
  a2 += __shfl_xor(a2, 16); a3 += __shfl_xor(a3, 16);
  a4 += __shfl_xor(a4, 16); a5 += __shfl_xor(a5, 16);
  a6 += __shfl_xor(a6, 16); a7 += __shfl_xor(a7, 16);

  float inv = 1.0f / fmaxf((float)deg, 1.0f);
  int c0 = cg << 3;
  size_t base = (size_t)row * 128;
  float4 blo = *(const float4*)(b1l + c0);
  float4 bhi = *(const float4*)(b1l + c0 + 4);
  uint4 rv = *(const uint4*)(hres + base + c0);
  float t0 = a0 * inv + blo.x + bf2f_lo(rv.x);
  float t1 = a1 * inv + blo.y + bf2f_hi(rv.x);
  float t2 = a2 * inv + blo.z + bf2f_lo(rv.y);
  float t3 = a3 * inv + blo.w + bf2f_hi(rv.y);
  float t4 = a4 * inv + bhi.x + bf2f_lo(rv.z);
  float t5 = a5 * inv + bhi.y + bf2f_hi(rv.z);
  float t6 = a6 * inv + bhi.z + bf2f_lo(rv.w);
  float t7 = a7 * inv + bhi.w + bf2f_hi(rv.w);

  float s = ((t0 + t1) + (t2 + t3)) + ((t4 + t5) + (t6 + t7));
#pragma unroll
  for (int m = 8; m >= 1; m >>= 1) s += __shfl_xor(s, m);  // 16-lane group
  float mu = s * (1.0f / 128.0f);
  float d0 = t0 - mu, d1 = t1 - mu, d2 = t2 - mu, d3 = t3 - mu;
  float d4 = t4 - mu, d5 = t5 - mu, d6 = t6 - mu, d7 = t7 - mu;
  float vv = ((d0 * d0 + d1 * d1) + (d2 * d2 + d3 * d3)) +
             ((d4 * d4 + d5 * d5) + (d6 * d6 + d7 * d7));
#pragma unroll
  for (int m = 8; m >= 1; m >>= 1) vv += __shfl_xor(vv, m);
  float rstd = rsqrtf(vv * (1.0f / 128.0f) + 1e-5f);
  if (eh == 0) {
    float4 glo = *(const float4*)(g + c0);
    float4 ghi = *(const float4*)(g + c0 + 4);
    float4 blo2 = *(const float4*)(b + c0);
    float4 bhi2 = *(const float4*)(b + c0 + 4);
    float h0 = fmaxf(d0 * rstd * glo.x + blo2.x, 0.0f);
    float h1 = fmaxf(d1 * rstd * glo.y + blo2.y, 0.0f);
    float h2 = fmaxf(d2 * rstd * glo.z + blo2.z, 0.0f);
    float h3 = fmaxf(d3 * rstd * glo.w + blo2.w, 0.0f);
    float h4 = fmaxf(d4 * rstd * ghi.x + bhi2.x, 0.0f);
    float h5 = fmaxf(d5 * rstd * ghi.y + bhi2.y, 0.0f);
    float h6 = fmaxf(d6 * rstd * ghi.z + bhi2.z, 0.0f);
    float h7 = fmaxf(d7 * rstd * ghi.w + bhi2.w, 0.0f);
    uint4 hv;
    hv.x = (unsigned int)f2bf(h0) | ((unsigned int)f2bf(h1) << 16);
    hv.y = (unsigned int)f2bf(h2) | ((unsigned int)f2bf(h3) << 16);
    hv.z = (unsigned int)f2bf(h4) | ((unsigned int)f2bf(h5) << 16);
    hv.w = (unsigned int)f2bf(h6) | ((unsigned int)f2bf(h7) << 16);
    *(uint4*)(hres + base + c0) = hv;
  }
}

// ---------------------------------------------------------------------------
// Layer-2 gather + epilogue: out = l2norm(mean_agg(z2) + b2l + r2), fp32 out.
// Same 2-row/wave structure with the parity-matched shfl scheme; z2 row =
// 64 bf16 = 128B, lane loads uint2 (4 cols).
// ---------------------------------------------------------------------------
__global__ __launch_bounds__(256) void gather_l2norm(
    const int* __restrict__ rowptr, const int* __restrict__ adj,
    const unsigned short* __restrict__ z2, const unsigned short* __restrict__ r2,
    const float* __restrict__ b2l, float* __restrict__ out) {
  const int lane = threadIdx.x & 63;
  const int wave = threadIdx.x >> 6;
  const int half = lane >> 5;
  const int l5 = lane & 31;
  const int eh = l5 >> 4;
  const int cg = lane & 15;         // col group: 4 cols
  const int row = blockIdx.x * 8 + wave * 2 + half;

  int e0 = rowptr[row], e1 = rowptr[row + 1];
  int deg = e1 - e0;
  float a0 = 0.f, a1 = 0.f, a2 = 0.f, a3 = 0.f;

  for (int be = 0; be < deg; be += 32) {
    int chunk = min(deg - be, 32);
    int ledge = ((l5 & 15) << 1) + eh;
    int my = 0;
    if (ledge < chunk) my = adj[e0 + be + ledge];
#pragma unroll 1
    for (int j = 0; j < chunk; j += 16) {
#pragma unroll
      for (int u = 0; u < 8; ++u) {
        int s = __shfl(my, (half << 5) + (eh << 4) + ((j >> 1) + u));
        if (j + 2 * u + eh < chunk) {
          uint2 v = *(const uint2*)(z2 + ((size_t)s << 6) + (cg << 2));
          a0 += bf2f_lo(v.x); a1 += bf2f_hi(v.x);
          a2 += bf2f_lo(v.y); a3 += bf2f_hi(v.y);
        }
      }
    }
  }
  a0 += __shfl_xor(a0, 16); a1 += __shfl_xor(a1, 16);
  a2 += __shfl_xor(a2, 16); a3 += __shfl_xor(a3, 16);

  float inv = 1.0f / fmaxf((float)deg, 1.0f);
  int c0 = cg << 2;
  size_t base = (size_t)row * 64;
  float4 bias = *(const float4*)(b2l + c0);
  uint2 rv = *(const uint2*)(r2 + base + c0);
  float t0 = a0 * inv + bias.x + bf2f_lo(rv.x);
  float t1 = a1 * inv + bias.y + bf2f_hi(rv.x);
  float t2 = a2 * inv + bias.z + bf2f_lo(rv.y);
  float t3 = a3 * inv + bias.w + bf2f_hi(rv.y);
  float s = (t0 * t0 + t1 * t1) + (t2 * t2 + t3 * t3);
#pragma unroll
  for (int m = 8; m >= 1; m >>= 1) s += __shfl_xor(s, m);
  float nrm = fmaxf(sqrtf(s), 1e-12f);
  if (eh == 0) {
    float4 o;
    o.x = t0 / nrm; o.y = t1 / nrm; o.z = t2 / nrm; o.w = t3 / nrm;
    *(float4*)(out + base + c0) = o;
  }
}

// Standalone GEMM wrapper (layer 2).
template <int NCOLS, bool ABF16>
__global__ __launch_bounds__(256) void gemm_mfma(
    const void* __restrict__ Av, const short* __restrict__ Bswz,
    unsigned short* __restrict__ outL, unsigned short* __restrict__ outR,
    int nrows) {
  gemm_body<NCOLS, ABF16>(blockIdx.x, Av, Bswz, outL, outR, nrows);
}

extern "C" void kernel_launch(void* const* d_in, const int* in_sizes, int n_in,
                              void* d_out, int out_size, void* d_ws, size_t ws_size,
                              hipStream_t stream) {
  const float* x   = (const float*)d_in[0];
  const int*   ei  = (const int*)d_in[1];
  const float* W1l = (const float*)d_in[2];
  const float* b1l = (const float*)d_in[3];
  const float* W1r = (const float*)d_in[4];
  const float* lng = (const float*)d_in[5];
  const float* lnb = (const float*)d_in[6];
  const float* W2l = (const float*)d_in[7];
  const float* b2l = (const float*)d_in[8];
  const float* W2r = (const float*)d_in[9];
  float* out = (float*)d_out;

  const int N = NNODES;

  unsigned short* y1b = (unsigned short*)d_ws;           // N*128 bf16
  unsigned short* r1b = y1b + (size_t)N * 128;           // N*128 (r1, then h)
  unsigned short* z2b = r1b + (size_t)N * 128;           // N*64
  unsigned short* r2b = z2b + (size_t)N * 64;            // N*64
  short* bswz1 = (short*)(r2b + (size_t)N * 64);         // 32768
  short* bswz2 = bswz1 + 32768;                          // 16384
  int* rowptr = (int*)(bswz2 + 16384);                   // N+1
  int* adj    = rowptr + (N + 1);                        // E
  unsigned int* part = (unsigned int*)(adj + NEDGES);    // E
  int* bcnt  = (int*)(part + NEDGES);                    // NBUCK
  int* bexcl = bcnt + NBUCK;                             // NBUCK+1
  int* bcur  = bexcl + NBUCK + 1;                        // NBUCK

  hipMemsetAsync(bcnt, 0, NBUCK * sizeof(int), stream);

  // front1 = bucket_count || prep_b(W1) || prep_b(W2)
  front1<<<NBLK_A + 128 + 64, 256, 0, stream>>>(ei, bcnt, W1l, W1r, bswz1,
                                                W2l, W2r, bswz2);
  bucket_scan<<<1, 512, 0, stream>>>(bcnt, bexcl, bcur);
  // front2 = GEMM1 ([y1|r1] = x @ [W1l|W1r]) || bucket_partition
  front2<<<GEMM_BLOCKS + NBLK_A, 256, 0, stream>>>(x, bswz1, y1b, r1b, ei,
                                                   bcur, part);
  bucket_build<<<NBUCK, 256, 0, stream>>>(part, bexcl, rowptr, adj);

  const int gat_blocks = N / 8;  // 12500 (N % 8 == 0)

  // Layer 1 epilogue: pull-aggregate y1; fused mean+bias+residual+LN+ReLU.
  gather_ln_relu<<<gat_blocks, 256, 0, stream>>>(rowptr, adj, y1b, r1b, b1l, lng, lnb);

  // Layer 2: [z2 | r2] = h @ [W2l|W2r]; pull-aggregate z2; fused
  // mean+bias+residual+L2norm -> out (fp32).
  gemm_mfma<128, true><<<GEMM_BLOCKS, 256, 0, stream>>>(r1b, bswz2, z2b, r2b, N);
  gather_l2norm<<<gat_blocks, 256, 0, stream>>>(rowptr, adj, z2b, r2b, b2l, out);
}

// Round 9
// 218.274 us; speedup vs baseline: 20.0088x; 1.0390x over previous
//
#include <hip/hip_runtime.h>
#include <hip/hip_bf16.h>

#define NNODES 100000
#define NEDGES 1600000
#define NBUCK 391        // ceil(NNODES / 256), 256 nodes per bucket
#define BUCK_SHIFT 8
#define NBLK_A 782       // ceil(NEDGES / 2048)
#define GEMM_BLOCKS 1563 // ceil(NNODES / 64)
#define SMEM_BYTES 17408 // 64*136*2 — union buffer for fused kernels

typedef short short8 __attribute__((ext_vector_type(8)));
typedef float floatx4 __attribute__((ext_vector_type(4)));

__device__ inline float bf2f_lo(unsigned int v) {
  union { unsigned int i; float f; } u; u.i = v << 16; return u.f;
}
__device__ inline float bf2f_hi(unsigned int v) {
  union { unsigned int i; float f; } u; u.i = v & 0xffff0000u; return u.f;
}
__device__ inline unsigned short f2bf(float f) {  // RNE
  union { float f; unsigned int i; } u; u.f = f;
  unsigned int r = u.i + 0x7fffu + ((u.i >> 16) & 1u);
  return (unsigned short)(r >> 16);
}

// ---------------------------------------------------------------------------
// Weight prep body: Bcat = [Wl | Wr] (128 x 2*half) -> bf16 fragment-
// contiguous layout for the GEMM's B-panel register loads.
// ---------------------------------------------------------------------------
__device__ void prep_body(int bid, int nblk, const float* __restrict__ Wl,
                          const float* __restrict__ Wr,
                          short* __restrict__ Bswz, int half) {
  int total = 128 * 2 * half;
  int stride = nblk * 256;
  for (int i = bid * 256 + threadIdx.x; i < total; i += stride) {
    int j = i & 7;
    int lane = (i >> 3) & 63;
    int f = i >> 9;  // frag id = ct*4 + ks
    int ks = f & 3, ct = f >> 2;
    int k = ks * 32 + ((lane >> 4) << 3) + j;
    int c = ct * 16 + (lane & 15);
    float v = (c < half) ? Wl[k * half + c] : Wr[k * half + (c - half)];
    Bswz[i] = (short)f2bf(v);
  }
}

// ---------------------------------------------------------------------------
// MFMA GEMM body: C = A @ Bcat, A: nrows x 128 (fp32 or bf16), Bcat: 128 x
// NCOLS. 4 waves, 64 rows/block; swapped operands. C is written back through
// an LDS re-assembly stage (reusing the A-tile buffer) so global stores are
// fully coalesced uint4 runs instead of 16-way-scattered ushort4s.
// ---------------------------------------------------------------------------
template <int NCOLS, bool ABF16>
__device__ void gemm_body(int bid, const void* __restrict__ Av,
                          const short* __restrict__ Bswz,
                          unsigned short* __restrict__ outL,
                          unsigned short* __restrict__ outR, int nrows,
                          char* smem) {
  constexpr int PW = NCOLS / 4;
  constexpr int CT = PW / 16;
  constexpr int HALF = NCOLS / 2;
  auto At = (unsigned short (*)[136])smem;  // [64][136]

  const int tid = threadIdx.x;
  const int lane = tid & 63;
  const int wave = tid >> 6;
  const int row0 = bid * 64;

  if (ABF16) {
    const unsigned short* A = (const unsigned short*)Av;
    for (int i = tid; i < 64 * 16; i += 256) {
      int r = i >> 4, c8 = (i & 15) << 3;
      int gr = row0 + r;
      uint4 v = make_uint4(0, 0, 0, 0);
      if (gr < nrows) v = *(const uint4*)(A + (size_t)gr * 128 + c8);
      *(uint4*)&At[r][c8] = v;
    }
  } else {
    const float* A = (const float*)Av;
    for (int i = tid; i < 64 * 32; i += 256) {
      int r = i >> 5, c4 = (i & 31) << 2;
      int gr = row0 + r;
      float4 v = make_float4(0.f, 0.f, 0.f, 0.f);
      if (gr < nrows) v = *(const float4*)(A + (size_t)gr * 128 + c4);
      ushort4 u = make_ushort4(f2bf(v.x), f2bf(v.y), f2bf(v.z), f2bf(v.w));
      *(ushort4*)&At[r][c4] = u;
    }
  }
  __syncthreads();

  short8 bfrag[CT][4];
#pragma unroll
  for (int ct = 0; ct < CT; ++ct)
#pragma unroll
    for (int ks = 0; ks < 4; ++ks)
      bfrag[ct][ks] =
          *(const short8*)(Bswz + ((((wave * CT + ct) * 4 + ks) * 64 + lane) << 3));

  floatx4 acc[4][CT];
#pragma unroll
  for (int rt = 0; rt < 4; ++rt)
#pragma unroll
    for (int ct = 0; ct < CT; ++ct) acc[rt][ct] = (floatx4)(0.f);

#pragma unroll
  for (int rt = 0; rt < 4; ++rt) {
#pragma unroll
    for (int ks = 0; ks < 4; ++ks) {
      short8 af = *(const short8*)&At[rt * 16 + (lane & 15)][ks * 32 + ((lane >> 4) << 3)];
#pragma unroll
      for (int ct = 0; ct < CT; ++ct)
        acc[rt][ct] = __builtin_amdgcn_mfma_f32_16x16x32_bf16(
            bfrag[ct][ks], af, acc[rt][ct], 0, 0, 0);
    }
  }
  __syncthreads();  // all LDS A-reads complete; reuse smem for C staging

  // C write-back: assemble 32-row (NCOLS=256) or 64-row (NCOLS=128) slabs
  // in LDS, then store coalesced uint4 runs.
  constexpr int CPAD = NCOLS + 8;
  constexpr int NPASS = (NCOLS == 256) ? 2 : 1;
  constexpr int ROWSP = 64 / NPASS;
  constexpr int RTP = 4 / NPASS;
  auto Cs = (unsigned short (*)[CPAD])smem;

#pragma unroll
  for (int p = 0; p < NPASS; ++p) {
    if (p) __syncthreads();
#pragma unroll
    for (int rr = 0; rr < RTP; ++rr) {
      int rt = p * RTP + rr;
      int rl = rr * 16 + (lane & 15);
#pragma unroll
      for (int ct = 0; ct < CT; ++ct) {
        int c = wave * PW + ct * 16 + ((lane >> 4) << 2);
        floatx4 a = acc[rt][ct];
        ushort4 u = make_ushort4(f2bf(a[0]), f2bf(a[1]), f2bf(a[2]), f2bf(a[3]));
        *(ushort4*)&Cs[rl][c] = u;
      }
    }
    __syncthreads();
    constexpr int CHUNKS = ROWSP * NCOLS / 8;  // uint4 chunks per pass
    for (int i = tid; i < CHUNKS; i += 256) {
      int rl = i / (NCOLS / 8);
      int cpos = (i % (NCOLS / 8)) * 8;
      int gr = row0 + p * ROWSP + rl;
      if (gr < nrows) {
        uint4 v = *(const uint4*)&Cs[rl][cpos];
        if (cpos < HALF)
          *(uint4*)(outL + (size_t)gr * HALF + cpos) = v;
        else
          *(uint4*)(outR + (size_t)gr * HALF + (cpos - HALF)) = v;
      }
    }
  }
}

// ---------------------------------------------------------------------------
// CSR build bodies (bucketed counting sort).
// ---------------------------------------------------------------------------
__device__ void count_body(int bid, const int* __restrict__ dsts,
                           int* __restrict__ bcnt) {
  __shared__ int h[NBUCK];
  for (int i = threadIdx.x; i < NBUCK; i += 256) h[i] = 0;
  __syncthreads();
  int e0 = bid * 2048;
  int eend = min(e0 + 2048, NEDGES);
  for (int e = e0 + threadIdx.x; e < eend; e += 256)
    atomicAdd(&h[dsts[e] >> BUCK_SHIFT], 1);
  __syncthreads();
  for (int i = threadIdx.x; i < NBUCK; i += 256)
    if (h[i]) atomicAdd(&bcnt[i], h[i]);
}

__device__ void partition_body(int bid, const int* __restrict__ ei,
                               int* __restrict__ bcur,
                               unsigned int* __restrict__ part, char* smem) {
  int* h = (int*)smem;          // NBUCK
  int* r = h + NBUCK;           // NBUCK
  for (int i = threadIdx.x; i < NBUCK; i += 256) { h[i] = 0; r[i] = 0; }
  __syncthreads();
  int e0 = bid * 2048;
  int eend = min(e0 + 2048, NEDGES);
  for (int e = e0 + threadIdx.x; e < eend; e += 256)
    atomicAdd(&h[ei[NEDGES + e] >> BUCK_SHIFT], 1);
  __syncthreads();
  for (int i = threadIdx.x; i < NBUCK; i += 256) {
    int c = h[i];
    h[i] = c ? atomicAdd(&bcur[i], c) : 0;
  }
  __syncthreads();
  for (int e = e0 + threadIdx.x; e < eend; e += 256) {
    int s = ei[e], d = ei[NEDGES + e];
    int b = d >> BUCK_SHIFT;
    int pos = h[b] + atomicAdd(&r[b], 1);
    part[pos] = (unsigned int)s | ((unsigned int)(d & 255) << 24);
  }
}

// front1 = bucket_count (782) || prep_b W1 (128) || prep_b W2 (64)
__global__ __launch_bounds__(256) void front1(
    const int* __restrict__ ei, int* __restrict__ bcnt,
    const float* __restrict__ W1l, const float* __restrict__ W1r,
    short* __restrict__ bswz1, const float* __restrict__ W2l,
    const float* __restrict__ W2r, short* __restrict__ bswz2) {
  int bid = blockIdx.x;
  if (bid < NBLK_A) {
    count_body(bid, ei + NEDGES, bcnt);
  } else if (bid < NBLK_A + 128) {
    prep_body(bid - NBLK_A, 128, W1l, W1r, bswz1, 128);
  } else {
    prep_body(bid - NBLK_A - 128, 64, W2l, W2r, bswz2, 64);
  }
}

// front2 = GEMM1 (1563) || bucket_partition (782), LDS overlaid (17.4KB).
__global__ __launch_bounds__(256) void front2(
    const float* __restrict__ x, const short* __restrict__ bswz1,
    unsigned short* __restrict__ y1b, unsigned short* __restrict__ r1b,
    const int* __restrict__ ei, int* __restrict__ bcur,
    unsigned int* __restrict__ part) {
  __shared__ char smem[SMEM_BYTES];
  int bid = blockIdx.x;
  if (bid < GEMM_BLOCKS) {
    gemm_body<256, false>(bid, x, bswz1, y1b, r1b, NNODES, smem);
  } else {
    partition_body(bid - GEMM_BLOCKS, ei, bcur, part, smem);
  }
}

__global__ __launch_bounds__(512) void bucket_scan(const int* __restrict__ bcnt,
                                                   int* __restrict__ bexcl,
                                                   int* __restrict__ bcur) {
  __shared__ int sm[512];
  int t = threadIdx.x;
  int v = (t < NBUCK) ? bcnt[t] : 0;
  int acc = v;
  sm[t] = acc;
  __syncthreads();
  for (int off = 1; off < 512; off <<= 1) {
    int add = (t >= off) ? sm[t - off] : 0;
    __syncthreads();
    acc += add;
    sm[t] = acc;
    __syncthreads();
  }
  if (t < NBUCK) {
    bexcl[t] = acc - v;
    bcur[t] = acc - v;
  }
  if (t == 0) bexcl[NBUCK] = NEDGES;
}

__global__ __launch_bounds__(256) void bucket_build(
    const unsigned int* __restrict__ part, const int* __restrict__ bexcl,
    int* __restrict__ rowptr, int* __restrict__ adj) {
  __shared__ int h[256], ex[256];
  int b = blockIdx.x;
  int t = threadIdx.x;
  int base = bexcl[b], end = bexcl[b + 1];
  h[t] = 0;
  __syncthreads();
  for (int i = base + t; i < end; i += 256)
    atomicAdd(&h[part[i] >> 24], 1);
  __syncthreads();
  int v = h[t];
  int acc = v;
  ex[t] = acc;
  __syncthreads();
  for (int off = 1; off < 256; off <<= 1) {
    int add = (t >= off) ? ex[t - off] : 0;
    __syncthreads();
    acc += add;
    ex[t] = acc;
    __syncthreads();
  }
  int excl = acc - v;
  int node = (b << BUCK_SHIFT) + t;
  if (node < NNODES) rowptr[node] = base + excl;
  if (b == 0 && t == 0) rowptr[NNODES] = NEDGES;
  h[t] = 0;
  ex[t] = excl;
  __syncthreads();
  for (int i = base + t; i < end; i += 256) {
    unsigned int p = part[i];
    int ld = p >> 24;
    int rank = atomicAdd(&h[ld], 1);
    adj[base + ex[ld] + rank] = (int)(p & 0xFFFFFFu);
  }
}

// ---------------------------------------------------------------------------
// Layer-1 gather + epilogue: h = relu(LN(mean_agg(y1) + b1l + r1)), bf16 feat.
// 2 rows per wave; parity-matched shfl broadcast (source lane active iff
// reader active). h overwrites r1 in place (bf16). NNODES % 8 == 0.
// ---------------------------------------------------------------------------
__global__ __launch_bounds__(256) void gather_ln_relu(
    const int* __restrict__ rowptr, const int* __restrict__ adj,
    const unsigned short* __restrict__ feat, unsigned short* __restrict__ hres,
    const float* __restrict__ b1l, const float* __restrict__ g,
    const float* __restrict__ b) {
  const int lane = threadIdx.x & 63;
  const int wave = threadIdx.x >> 6;
  const int half = lane >> 5;       // 0 = row A, 1 = row B
  const int l5 = lane & 31;
  const int eh = l5 >> 4;           // edge-parity subgroup
  const int cg = lane & 15;         // col group: 8 cols
  const int row = blockIdx.x * 8 + wave * 2 + half;
  const int cgo = cg << 3;

  int e0 = rowptr[row], e1 = rowptr[row + 1];
  int deg = e1 - e0;
  float a0 = 0.f, a1 = 0.f, a2 = 0.f, a3 = 0.f;
  float a4 = 0.f, a5 = 0.f, a6 = 0.f, a7 = 0.f;

  for (int be = 0; be < deg; be += 32) {
    int chunk = min(deg - be, 32);
    int ledge = ((l5 & 15) << 1) + eh;     // parity-matched adj assignment
    int my = 0;
    if (ledge < chunk) my = adj[e0 + be + ledge];
#pragma unroll 1
    for (int j = 0; j < chunk; j += 16) {
#pragma unroll
      for (int u = 0; u < 8; ++u) {
        int s = __shfl(my, (half << 5) + (eh << 4) + ((j >> 1) + u));
        if (j + 2 * u + eh < chunk) {
          uint4 v = *(const uint4*)(feat + ((size_t)s << 7) + cgo);
          a0 += bf2f_lo(v.x); a1 += bf2f_hi(v.x);
          a2 += bf2f_lo(v.y); a3 += bf2f_hi(v.y);
          a4 += bf2f_lo(v.z); a5 += bf2f_hi(v.z);
          a6 += bf2f_lo(v.w); a7 += bf2f_hi(v.w);
        }
      }
    }
  }
  a0 += __shfl_xor(a0, 16); a1 += __shfl_xor(a1, 16);
  a2 += __shfl_xor(a2, 16); a3 += __shfl_xor(a3, 16);
  a4 += __shfl_xor(a4, 16); a5 += __shfl_xor(a5, 16);
  a6 += __shfl_xor(a6, 16); a7 += __shfl_xor(a7, 16);

  float inv = 1.0f / fmaxf((float)deg, 1.0f);
  int c0 = cg << 3;
  size_t base = (size_t)row * 128;
  float4 blo = *(const float4*)(b1l + c0);
  float4 bhi = *(const float4*)(b1l + c0 + 4);
  uint4 rv = *(const uint4*)(hres + base + c0);
  float t0 = a0 * inv + blo.x + bf2f_lo(rv.x);
  float t1 = a1 * inv + blo.y + bf2f_hi(rv.x);
  float t2 = a2 * inv + blo.z + bf2f_lo(rv.y);
  float t3 = a3 * inv + blo.w + bf2f_hi(rv.y);
  float t4 = a4 * inv + bhi.x + bf2f_lo(rv.z);
  float t5 = a5 * inv + bhi.y + bf2f_hi(rv.z);
  float t6 = a6 * inv + bhi.z + bf2f_lo(rv.w);
  float t7 = a7 * inv + bhi.w + bf2f_hi(rv.w);

  float s = ((t0 + t1) + (t2 + t3)) + ((t4 + t5) + (t6 + t7));
#pragma unroll
  for (int m = 8; m >= 1; m >>= 1) s += __shfl_xor(s, m);
  float mu = s * (1.0f / 128.0f);
  float d0 = t0 - mu, d1 = t1 - mu, d2 = t2 - mu, d3 = t3 - mu;
  float d4 = t4 - mu, d5 = t5 - mu, d6 = t6 - mu, d7 = t7 - mu;
  float vv = ((d0 * d0 + d1 * d1) + (d2 * d2 + d3 * d3)) +
             ((d4 * d4 + d5 * d5) + (d6 * d6 + d7 * d7));
#pragma unroll
  for (int m = 8; m >= 1; m >>= 1) vv += __shfl_xor(vv, m);
  float rstd = rsqrtf(vv * (1.0f / 128.0f) + 1e-5f);
  if (eh == 0) {
    float4 glo = *(const float4*)(g + c0);
    float4 ghi = *(const float4*)(g + c0 + 4);
    float4 blo2 = *(const float4*)(b + c0);
    float4 bhi2 = *(const float4*)(b + c0 + 4);
    float h0 = fmaxf(d0 * rstd * glo.x + blo2.x, 0.0f);
    float h1 = fmaxf(d1 * rstd * glo.y + blo2.y, 0.0f);
    float h2 = fmaxf(d2 * rstd * glo.z + blo2.z, 0.0f);
    float h3 = fmaxf(d3 * rstd * glo.w + blo2.w, 0.0f);
    float h4 = fmaxf(d4 * rstd * ghi.x + bhi2.x, 0.0f);
    float h5 = fmaxf(d5 * rstd * ghi.y + bhi2.y, 0.0f);
    float h6 = fmaxf(d6 * rstd * ghi.z + bhi2.z, 0.0f);
    float h7 = fmaxf(d7 * rstd * ghi.w + bhi2.w, 0.0f);
    uint4 hv;
    hv.x = (unsigned int)f2bf(h0) | ((unsigned int)f2bf(h1) << 16);
    hv.y = (unsigned int)f2bf(h2) | ((unsigned int)f2bf(h3) << 16);
    hv.z = (unsigned int)f2bf(h4) | ((unsigned int)f2bf(h5) << 16);
    hv.w = (unsigned int)f2bf(h6) | ((unsigned int)f2bf(h7) << 16);
    *(uint4*)(hres + base + c0) = hv;
  }
}

// ---------------------------------------------------------------------------
// Layer-2 gather + epilogue: out = l2norm(mean_agg(z2) + b2l + r2), fp32 out.
// ---------------------------------------------------------------------------
__global__ __launch_bounds__(256) void gather_l2norm(
    const int* __restrict__ rowptr, const int* __restrict__ adj,
    const unsigned short* __restrict__ z2, const unsigned short* __restrict__ r2,
    const float* __restrict__ b2l, float* __restrict__ out) {
  const int lane = threadIdx.x & 63;
  const int wave = threadIdx.x >> 6;
  const int half = lane >> 5;
  const int l5 = lane & 31;
  const int eh = l5 >> 4;
  const int cg = lane & 15;
  const int row = blockIdx.x * 8 + wave * 2 + half;

  int e0 = rowptr[row], e1 = rowptr[row + 1];
  int deg = e1 - e0;
  float a0 = 0.f, a1 = 0.f, a2 = 0.f, a3 = 0.f;

  for (int be = 0; be < deg; be += 32) {
    int chunk = min(deg - be, 32);
    int ledge = ((l5 & 15) << 1) + eh;
    int my = 0;
    if (ledge < chunk) my = adj[e0 + be + ledge];
#pragma unroll 1
    for (int j = 0; j < chunk; j += 16) {
#pragma unroll
      for (int u = 0; u < 8; ++u) {
        int s = __shfl(my, (half << 5) + (eh << 4) + ((j >> 1) + u));
        if (j + 2 * u + eh < chunk) {
          uint2 v = *(const uint2*)(z2 + ((size_t)s << 6) + (cg << 2));
          a0 += bf2f_lo(v.x); a1 += bf2f_hi(v.x);
          a2 += bf2f_lo(v.y); a3 += bf2f_hi(v.y);
        }
      }
    }
  }
  a0 += __shfl_xor(a0, 16); a1 += __shfl_xor(a1, 16);
  a2 += __shfl_xor(a2, 16); a3 += __shfl_xor(a3, 16);

  float inv = 1.0f / fmaxf((float)deg, 1.0f);
  int c0 = cg << 2;
  size_t base = (size_t)row * 64;
  float4 bias = *(const float4*)(b2l + c0);
  uint2 rv = *(const uint2*)(r2 + base + c0);
  float t0 = a0 * inv + bias.x + bf2f_lo(rv.x);
  float t1 = a1 * inv + bias.y + bf2f_hi(rv.x);
  float t2 = a2 * inv + bias.z + bf2f_lo(rv.y);
  float t3 = a3 * inv + bias.w + bf2f_hi(rv.y);
  float s = (t0 * t0 + t1 * t1) + (t2 * t2 + t3 * t3);
#pragma unroll
  for (int m = 8; m >= 1; m >>= 1) s += __shfl_xor(s, m);
  float nrm = fmaxf(sqrtf(s), 1e-12f);
  if (eh == 0) {
    float4 o;
    o.x = t0 / nrm; o.y = t1 / nrm; o.z = t2 / nrm; o.w = t3 / nrm;
    *(float4*)(out + base + c0) = o;
  }
}

// Standalone GEMM wrapper (layer 2).
template <int NCOLS, bool ABF16>
__global__ __launch_bounds__(256) void gemm_mfma(
    const void* __restrict__ Av, const short* __restrict__ Bswz,
    unsigned short* __restrict__ outL, unsigned short* __restrict__ outR,
    int nrows) {
  __shared__ char smem[SMEM_BYTES];
  gemm_body<NCOLS, ABF16>(blockIdx.x, Av, Bswz, outL, outR, nrows, smem);
}

extern "C" void kernel_launch(void* const* d_in, const int* in_sizes, int n_in,
                              void* d_out, int out_size, void* d_ws, size_t ws_size,
                              hipStream_t stream) {
  const float* x   = (const float*)d_in[0];
  const int*   ei  = (const int*)d_in[1];
  const float* W1l = (const float*)d_in[2];
  const float* b1l = (const float*)d_in[3];
  const float* W1r = (const float*)d_in[4];
  const float* lng = (const float*)d_in[5];
  const float* lnb = (const float*)d_in[6];
  const float* W2l = (const float*)d_in[7];
  const float* b2l = (const float*)d_in[8];
  const float* W2r = (const float*)d_in[9];
  float* out = (float*)d_out;

  const int N = NNODES;

  unsigned short* y1b = (unsigned short*)d_ws;           // N*128 bf16
  unsigned short* r1b = y1b + (size_t)N * 128;           // N*128 (r1, then h)
  unsigned short* z2b = r1b + (size_t)N * 128;           // N*64
  unsigned short* r2b = z2b + (size_t)N * 64;            // N*64
  short* bswz1 = (short*)(r2b + (size_t)N * 64);         // 32768
  short* bswz2 = bswz1 + 32768;                          // 16384
  int* rowptr = (int*)(bswz2 + 16384);                   // N+1
  int* adj    = rowptr + (N + 1);                        // E
  unsigned int* part = (unsigned int*)(adj + NEDGES);    // E
  int* bcnt  = (int*)(part + NEDGES);                    // NBUCK
  int* bexcl = bcnt + NBUCK;                             // NBUCK+1
  int* bcur  = bexcl + NBUCK + 1;                        // NBUCK

  hipMemsetAsync(bcnt, 0, NBUCK * sizeof(int), stream);

  // front1 = bucket_count || prep_b(W1) || prep_b(W2)
  front1<<<NBLK_A + 128 + 64, 256, 0, stream>>>(ei, bcnt, W1l, W1r, bswz1,
                                                W2l, W2r, bswz2);
  bucket_scan<<<1, 512, 0, stream>>>(bcnt, bexcl, bcur);
  // front2 = GEMM1 ([y1|r1] = x @ [W1l|W1r]) || bucket_partition
  front2<<<GEMM_BLOCKS + NBLK_A, 256, 0, stream>>>(x, bswz1, y1b, r1b, ei,
                                                   bcur, part);
  bucket_build<<<NBUCK, 256, 0, stream>>>(part, bexcl, rowptr, adj);

  const int gat_blocks = N / 8;  // 12500 (N % 8 == 0)

  // Layer 1 epilogue: pull-aggregate y1; fused mean+bias+residual+LN+ReLU.
  gather_ln_relu<<<gat_blocks, 256, 0, stream>>>(rowptr, adj, y1b, r1b, b1l, lng, lnb);

  // Layer 2: [z2 | r2] = h @ [W2l|W2r]; pull-aggregate z2; fused
  // mean+bias+residual+L2norm -> out (fp32).
  gemm_mfma<128, true><<<GEMM_BLOCKS, 256, 0, stream>>>(r1b, bswz2, z2b, r2b, N);
  gather_l2norm<<<gat_blocks, 256, 0, stream>>>(rowptr, adj, z2b, r2b, b2l, out);
}